// Round 1
// baseline (252.774 us; speedup 1.0000x reference)
//
#include <hip/hip_runtime.h>

#define T_SEQ 512
#define CDIM  1024
#define NH    16
#define DH    64
#define BB    2
#define KD    8

// exp(-32*d^2) = exp2(-32*log2(e)*d^2); 32*log2(e) = 46.16624130844683
#define BETA_LOG2E 46.16624131f
#define LOG2E      1.4426950408889634f

// ---------------------------------------------------------------------------
// fp32 tiled GEMM: C = A(MxK) @ B(KxN). 64x64 tile, K-step 32, 4x4 per thread.
// blockIdx.z selects among three B/C pointer pairs (QKV in one launch).
// ---------------------------------------------------------------------------
__global__ __launch_bounds__(256)
void gemm_f32_multi(const float* __restrict__ A,
                    const float* __restrict__ B0, const float* __restrict__ B1,
                    const float* __restrict__ B2,
                    float* __restrict__ C0, float* __restrict__ C1, float* __restrict__ C2,
                    int M, int N, int K)
{
    __shared__ float As[32][68];  // A^T tile: As[k][m]
    __shared__ float Bs[32][68];  // B tile:   Bs[k][n]

    const float* Bp = (blockIdx.z == 0) ? B0 : (blockIdx.z == 1 ? B1 : B2);
    float*       Cp = (blockIdx.z == 0) ? C0 : (blockIdx.z == 1 ? C1 : C2);

    const int tid = threadIdx.x;
    const int tx = tid & 15, ty = tid >> 4;
    const int m0 = blockIdx.y * 64, n0 = blockIdx.x * 64;

    const int ra = tid >> 2, ka = (tid & 3) * 8;   // A tile: 64 rows x 32 k
    const int rb = tid >> 3, cb = (tid & 7) * 8;   // B tile: 32 rows x 64 n

    float acc[4][4] = {};

    for (int k0 = 0; k0 < K; k0 += 32) {
        float4 a0 = *(const float4*)(A + (size_t)(m0 + ra) * K + k0 + ka);
        float4 a1 = *(const float4*)(A + (size_t)(m0 + ra) * K + k0 + ka + 4);
        float4 b0 = *(const float4*)(Bp + (size_t)(k0 + rb) * N + n0 + cb);
        float4 b1 = *(const float4*)(Bp + (size_t)(k0 + rb) * N + n0 + cb + 4);

        As[ka + 0][ra] = a0.x; As[ka + 1][ra] = a0.y;
        As[ka + 2][ra] = a0.z; As[ka + 3][ra] = a0.w;
        As[ka + 4][ra] = a1.x; As[ka + 5][ra] = a1.y;
        As[ka + 6][ra] = a1.z; As[ka + 7][ra] = a1.w;
        *(float4*)&Bs[rb][cb]     = b0;
        *(float4*)&Bs[rb][cb + 4] = b1;
        __syncthreads();

        #pragma unroll
        for (int kk = 0; kk < 32; ++kk) {
            float4 av = *(const float4*)&As[kk][ty * 4];
            float4 bv = *(const float4*)&Bs[kk][tx * 4];
            float a_[4] = {av.x, av.y, av.z, av.w};
            float b_[4] = {bv.x, bv.y, bv.z, bv.w};
            #pragma unroll
            for (int i = 0; i < 4; ++i)
                #pragma unroll
                for (int j = 0; j < 4; ++j)
                    acc[i][j] += a_[i] * b_[j];
        }
        __syncthreads();
    }

    #pragma unroll
    for (int i = 0; i < 4; ++i) {
        float4 o = make_float4(acc[i][0], acc[i][1], acc[i][2], acc[i][3]);
        *(float4*)(Cp + (size_t)(m0 + ty * 4 + i) * N + n0 + tx * 4) = o;
    }
}

// ---------------------------------------------------------------------------
// RoPE + RMS-norm + digit projection. One wave per (m = b*T+t, h).
// Normalized q/k are consumed ONLY by the digit projection, so only the
// 8 sigmoid digits are written out, layout (B,H,T,8).
// blockIdx.y: 0 -> (rawQ, Wdq, qdig), 1 -> (rawK, Wdk, kdig)
// ---------------------------------------------------------------------------
__global__ __launch_bounds__(256)
void rope_digits(const float* __restrict__ rawQ, const float* __restrict__ rawK,
                 const float* __restrict__ cosp, const float* __restrict__ sinp,
                 const float* __restrict__ Wdq, const float* __restrict__ Wdk,
                 float* __restrict__ qdig, float* __restrict__ kdig)
{
    const int tid = threadIdx.x;
    const int lane = tid & 63;
    const int u = blockIdx.x * 4 + (tid >> 6);  // (m,h) task id
    const int h = u & (NH - 1);
    const int m = u >> 4;
    const int t = m & (T_SEQ - 1);
    const int b = m >> 9;

    const float* raw = blockIdx.y ? rawK : rawQ;
    const float* Wd  = blockIdx.y ? Wdk  : Wdq;
    float*       dig = blockIdx.y ? kdig : qdig;

    float r = raw[(size_t)m * CDIM + h * DH + lane];
    float p = __shfl_xor(r, 32);
    const int d31 = lane & 31;
    float cv = cosp[t * 32 + d31];
    float sv = sinp[t * 32 + d31];
    float val = (lane < 32) ? (r * cv - p * sv) : (p * sv + r * cv);

    float ss = val * val;
    #pragma unroll
    for (int off = 1; off < 64; off <<= 1) ss += __shfl_xor(ss, off);
    float nrm = val * rsqrtf(ss * (1.0f / 64.0f) + 1e-6f);

    float wrow[8];
    *(float4*)&wrow[0] = *(const float4*)&Wd[lane * 8];
    *(float4*)&wrow[4] = *(const float4*)&Wd[lane * 8 + 4];

    float z[8];
    #pragma unroll
    for (int j = 0; j < 8; ++j) z[j] = nrm * wrow[j];
    #pragma unroll
    for (int j = 0; j < 8; ++j) {
        #pragma unroll
        for (int off = 1; off < 64; off <<= 1) z[j] += __shfl_xor(z[j], off);
    }

    if (lane == 0) {
        size_t base = ((size_t)(b * NH + h) * T_SEQ + t) * KD;
        #pragma unroll
        for (int j = 0; j < 8; ++j)
            dig[base + j] = 1.0f / (1.0f + exp2f(-LOG2E * z[j]));
    }
}

// ---------------------------------------------------------------------------
// Fused ultrametric causal attention.
// Block = (qchunk c, h, b), 256 threads = 4 waves. lane = local q row (64).
// Waves split k (kl = j*4 + w). weight = 2^lcp; accumulate unnormalized
// sum(w * v) + denom, cross-wave reduce in LDS, normalize, write y (B,T,C).
// ---------------------------------------------------------------------------
__global__ __launch_bounds__(256)
void attn_kernel(const float* __restrict__ qdig, const float* __restrict__ kdig,
                 const float* __restrict__ vraw, float* __restrict__ y)
{
    __shared__ float vs[64 * 64];    // v tile (k-local row major, stride 64)
    __shared__ float kds[64 * 8];    // k digits tile
    __shared__ float red[64 * 68];   // cross-wave reduction (stride 68)
    __shared__ float pden[4 * 64];   // per-wave denominators

    const int tid = threadIdx.x;
    const int w = tid >> 6, lane = tid & 63;
    const int c = blockIdx.x, h = blockIdx.y, b = blockIdx.z;
    const int q = c * 64 + lane;
    const size_t bhT = (size_t)(b * NH + h) * T_SEQ;

    float qd[8];
    {
        const float* qp = qdig + (bhT + q) * KD;
        *(float4*)&qd[0] = *(const float4*)qp;
        *(float4*)&qd[4] = *(const float4*)(qp + 4);
    }

    float4 acc[16];
    #pragma unroll
    for (int u2 = 0; u2 < 16; ++u2) acc[u2] = make_float4(0.f, 0.f, 0.f, 0.f);
    float den = 0.f;

    const int ntiles = c + 1;
    for (int kt = 0; kt < ntiles; ++kt) {
        const int k0 = kt * 64;
        __syncthreads();  // protect LDS from previous iteration's readers
        {
            const int r = tid >> 2, cq = (tid & 3) * 16;
            const float* src = vraw + ((size_t)(b * T_SEQ + k0 + r)) * CDIM + h * DH + cq;
            float4* dst = (float4*)&vs[r * 64 + cq];
            #pragma unroll
            for (int u2 = 0; u2 < 4; ++u2) dst[u2] = ((const float4*)src)[u2];
            const float* ksrc = kdig + (bhT + k0) * KD;
            *(float2*)&kds[tid * 2] = *(const float2*)&ksrc[tid * 2];
        }
        __syncthreads();

        for (int j = 0; j < 16; ++j) {
            const int kl = j * 4 + w;
            const int k = k0 + kl;
            float kd[8];
            *(float4*)&kd[0] = *(const float4*)&kds[kl * 8];
            *(float4*)&kd[4] = *(const float4*)&kds[kl * 8 + 4];

            float cum = 1.f, lcp = 0.f;
            #pragma unroll
            for (int jj = 0; jj < 8; ++jj) {
                float d = qd[jj] - kd[jj];
                cum *= exp2f(-BETA_LOG2E * d * d);
                lcp += cum;
            }
            float wgt = (k <= q) ? exp2f(lcp) : 0.f;
            den += wgt;

            const float4* vrow = (const float4*)&vs[kl * 64];
            #pragma unroll
            for (int u2 = 0; u2 < 16; ++u2) {
                float4 vv = vrow[u2];
                acc[u2].x += wgt * vv.x; acc[u2].y += wgt * vv.y;
                acc[u2].z += wgt * vv.z; acc[u2].w += wgt * vv.w;
            }
        }
    }

    pden[w * 64 + lane] = den;
    for (int wv = 0; wv < 4; ++wv) {
        if (w == wv) {
            float* pb = &red[lane * 68];
            if (wv == 0) {
                #pragma unroll
                for (int u2 = 0; u2 < 16; ++u2) *(float4*)&pb[u2 * 4] = acc[u2];
            } else {
                #pragma unroll
                for (int u2 = 0; u2 < 16; ++u2) {
                    float4 t0 = *(float4*)&pb[u2 * 4];
                    t0.x += acc[u2].x; t0.y += acc[u2].y;
                    t0.z += acc[u2].z; t0.w += acc[u2].w;
                    *(float4*)&pb[u2 * 4] = t0;
                }
            }
        }
        __syncthreads();
    }

    const int qr = tid >> 2, dg = (tid & 3) * 16;
    float den4 = pden[qr] + pden[64 + qr] + pden[128 + qr] + pden[192 + qr];
    float inv = 1.f / fmaxf(den4, 1e-9f);
    float* yr = y + ((size_t)(b * T_SEQ + c * 64 + qr)) * CDIM + h * DH + dg;
    #pragma unroll
    for (int u2 = 0; u2 < 16; ++u2) yr[u2] = red[qr * 68 + dg + u2] * inv;
}

// ---------------------------------------------------------------------------
extern "C" void kernel_launch(void* const* d_in, const int* in_sizes, int n_in,
                              void* d_out, int out_size, void* d_ws, size_t ws_size,
                              hipStream_t stream)
{
    (void)in_sizes; (void)n_in; (void)out_size; (void)ws_size;
    const float* x    = (const float*)d_in[0];
    const float* cosp = (const float*)d_in[1];
    const float* sinp = (const float*)d_in[2];
    const float* Wq   = (const float*)d_in[3];
    const float* Wk   = (const float*)d_in[4];
    const float* Wv   = (const float*)d_in[5];
    const float* Wo   = (const float*)d_in[6];
    const float* Wdq  = (const float*)d_in[7];
    const float* Wdk  = (const float*)d_in[8];
    float* out = (float*)d_out;
    float* ws  = (float*)d_ws;

    const int M = BB * T_SEQ;  // 1024
    float* rawQ = ws;
    float* rawK = rawQ + (size_t)M * CDIM;
    float* rawV = rawK + (size_t)M * CDIM;
    float* qdig = rawV + (size_t)M * CDIM;
    float* kdig = qdig + (size_t)M * NH * KD;
    float* ybuf = kdig + (size_t)M * NH * KD;

    dim3 blk(256);
    gemm_f32_multi<<<dim3(16, 16, 3), blk, 0, stream>>>(
        x, Wq, Wk, Wv, rawQ, rawK, rawV, M, CDIM, CDIM);
    rope_digits<<<dim3(4096, 2), blk, 0, stream>>>(
        rawQ, rawK, cosp, sinp, Wdq, Wdk, qdig, kdig);
    attn_kernel<<<dim3(8, NH, BB), blk, 0, stream>>>(qdig, kdig, rawV, ybuf);
    gemm_f32_multi<<<dim3(16, 16, 1), blk, 0, stream>>>(
        ybuf, Wo, Wo, Wo, out, out, out, M, CDIM, CDIM);
}

// Round 2
// 156.377 us; speedup vs baseline: 1.6164x; 1.6164x over previous
//
#include <hip/hip_runtime.h>

#define T_SEQ 512
#define CDIM  1024
#define NH    16
#define DH    64
#define BB    2
#define KD    8

#define BETA_LOG2E 46.16624131f   // 32*log2(e)
#define LOG2E      1.4426950408889634f

typedef unsigned short u16;
typedef __attribute__((ext_vector_type(8))) short bf16x8;
typedef __attribute__((ext_vector_type(4))) float f32x4;

__device__ inline u16 f2bf(float f) {
    unsigned int u = __builtin_bit_cast(unsigned int, f);
    unsigned int r = (u + 0x7fffu + ((u >> 16) & 1u)) >> 16;
    return (u16)r;
}

__device__ inline void gload_lds16(const void* g, void* l) {
    __builtin_amdgcn_global_load_lds(
        (const __attribute__((address_space(1))) void*)g,
        (__attribute__((address_space(3))) void*)l, 16, 0, 0);
}

// ---------------------------------------------------------------------------
// x (fp32, row-major) -> bf16, same layout. 8 elems/thread.
// ---------------------------------------------------------------------------
__global__ __launch_bounds__(256)
void convert_x(const float* __restrict__ src, u16* __restrict__ dst)
{
    int i = (blockIdx.x * 256 + threadIdx.x) * 8;
    float4 a = *(const float4*)(src + i);
    float4 b = *(const float4*)(src + i + 4);
    uint4 p;
    p.x = f2bf(a.x) | ((unsigned)f2bf(a.y) << 16);
    p.y = f2bf(a.z) | ((unsigned)f2bf(a.w) << 16);
    p.z = f2bf(b.x) | ((unsigned)f2bf(b.y) << 16);
    p.w = f2bf(b.z) | ((unsigned)f2bf(b.w) << 16);
    *(uint4*)(dst + i) = p;
}

// ---------------------------------------------------------------------------
// W [K][N] fp32 -> Wt [N][K] bf16 (32x32 LDS tile transpose). z selects matrix.
// ---------------------------------------------------------------------------
__global__ __launch_bounds__(256)
void transpose_bf16(const float* __restrict__ W0, const float* __restrict__ W1,
                    const float* __restrict__ W2, const float* __restrict__ W3,
                    u16* __restrict__ T0, u16* __restrict__ T1,
                    u16* __restrict__ T2, u16* __restrict__ T3)
{
    __shared__ u16 tile[32][33];
    const float* W = (blockIdx.z == 0) ? W0 : (blockIdx.z == 1) ? W1
                   : (blockIdx.z == 2) ? W2 : W3;
    u16* Tt        = (blockIdx.z == 0) ? T0 : (blockIdx.z == 1) ? T1
                   : (blockIdx.z == 2) ? T2 : T3;
    const int k0 = blockIdx.y * 32, n0 = blockIdx.x * 32;
    const int r = threadIdx.x >> 3, c4 = (threadIdx.x & 7) * 4;

    float4 v = *(const float4*)&W[(size_t)(k0 + r) * CDIM + n0 + c4];
    tile[r][c4 + 0] = f2bf(v.x);
    tile[r][c4 + 1] = f2bf(v.y);
    tile[r][c4 + 2] = f2bf(v.z);
    tile[r][c4 + 3] = f2bf(v.w);
    __syncthreads();
    ushort4 o;
    o.x = tile[c4 + 0][r];
    o.y = tile[c4 + 1][r];
    o.z = tile[c4 + 2][r];
    o.w = tile[c4 + 3][r];
    *(ushort4*)&Tt[(size_t)(n0 + r) * CDIM + k0 + c4] = o;
}

// ---------------------------------------------------------------------------
// bf16 MFMA GEMM: C(fp32) = A(bf16 [M][K]) @ W, with B given TRANSPOSED as
// Bt(bf16 [N][K]). 64x64 tile, BK=64, 4 waves of 32x32 (2x2 frags of
// 16x16x32). global_load_lds(16B) staging with XOR slot swizzle
// (slot ^= row&7) pre-applied on the GLOBAL source, swizzled ds_read_b128.
// blockIdx.z selects among three Bt/C pairs.
// ---------------------------------------------------------------------------
__global__ __launch_bounds__(256)
void gemm_bf16_multi(const u16* __restrict__ A,
                     const u16* __restrict__ B0, const u16* __restrict__ B1,
                     const u16* __restrict__ B2,
                     float* __restrict__ C0, float* __restrict__ C1,
                     float* __restrict__ C2,
                     int M, int N, int K)
{
    __shared__ u16 As[64 * 64];   // [row][k-slot*8], 128B rows, 8KB
    __shared__ u16 Bs[64 * 64];

    const u16* Bt = (blockIdx.z == 0) ? B0 : (blockIdx.z == 1) ? B1 : B2;
    float*     C  = (blockIdx.z == 0) ? C0 : (blockIdx.z == 1) ? C1 : C2;

    const int tid = threadIdx.x;
    const int l = tid & 63, w = tid >> 6;
    const int m0 = blockIdx.y * 64, n0 = blockIdx.x * 64;
    const int wr = (w >> 1) * 32, wc = (w & 1) * 32;

    // staging geometry: wave w, instr q covers rows w*16+q*8 .. +7
    const int srow = l >> 3;                  // 0..7
    const int sslot = (l & 7) ^ srow;         // swizzled 16B slot in source

    f32x4 acc[2][2];
    #pragma unroll
    for (int i = 0; i < 2; ++i)
        #pragma unroll
        for (int j = 0; j < 2; ++j)
            acc[i][j] = (f32x4){0.f, 0.f, 0.f, 0.f};

    for (int k0 = 0; k0 < K; k0 += 64) {
        __syncthreads();   // previous iteration's readers done
        #pragma unroll
        for (int q = 0; q < 2; ++q) {
            const int row = w * 16 + q * 8 + srow;
            gload_lds16(A  + (size_t)(m0 + row) * K + k0 + sslot * 8,
                        &As[(w * 16 + q * 8) * 64]);
            gload_lds16(Bt + (size_t)(n0 + row) * K + k0 + sslot * 8,
                        &Bs[(w * 16 + q * 8) * 64]);
        }
        __syncthreads();   // drains vmcnt(0) before barrier

        bf16x8 af[2][2], bf[2][2];
        #pragma unroll
        for (int i = 0; i < 2; ++i)
            #pragma unroll
            for (int kh = 0; kh < 2; ++kh) {
                const int ra = wr + i * 16 + (l & 15);
                const int sa = (kh * 4 + (l >> 4)) ^ (ra & 7);
                af[i][kh] = *(const bf16x8*)&As[ra * 64 + sa * 8];
                const int rb = wc + i * 16 + (l & 15);
                const int sb = (kh * 4 + (l >> 4)) ^ (rb & 7);
                bf[i][kh] = *(const bf16x8*)&Bs[rb * 64 + sb * 8];
            }
        #pragma unroll
        for (int kh = 0; kh < 2; ++kh)
            #pragma unroll
            for (int i = 0; i < 2; ++i)
                #pragma unroll
                for (int j = 0; j < 2; ++j)
                    acc[i][j] = __builtin_amdgcn_mfma_f32_16x16x32_bf16(
                        af[i][kh], bf[j][kh], acc[i][j], 0, 0, 0);
    }

    #pragma unroll
    for (int i = 0; i < 2; ++i)
        #pragma unroll
        for (int j = 0; j < 2; ++j) {
            const int row = m0 + wr + i * 16 + (l >> 4) * 4;
            const int col = n0 + wc + j * 16 + (l & 15);
            #pragma unroll
            for (int r = 0; r < 4; ++r)
                C[(size_t)(row + r) * N + col] = acc[i][j][r];
        }
}

// ---------------------------------------------------------------------------
// RoPE + RMS-norm + digit projection (unchanged from round 1).
// ---------------------------------------------------------------------------
__global__ __launch_bounds__(256)
void rope_digits(const float* __restrict__ rawQ, const float* __restrict__ rawK,
                 const float* __restrict__ cosp, const float* __restrict__ sinp,
                 const float* __restrict__ Wdq, const float* __restrict__ Wdk,
                 float* __restrict__ qdig, float* __restrict__ kdig)
{
    const int tid = threadIdx.x;
    const int lane = tid & 63;
    const int u = blockIdx.x * 4 + (tid >> 6);
    const int h = u & (NH - 1);
    const int m = u >> 4;
    const int t = m & (T_SEQ - 1);
    const int b = m >> 9;

    const float* raw = blockIdx.y ? rawK : rawQ;
    const float* Wd  = blockIdx.y ? Wdk  : Wdq;
    float*       dig = blockIdx.y ? kdig : qdig;

    float r = raw[(size_t)m * CDIM + h * DH + lane];
    float p = __shfl_xor(r, 32);
    const int d31 = lane & 31;
    float cv = cosp[t * 32 + d31];
    float sv = sinp[t * 32 + d31];
    float val = (lane < 32) ? (r * cv - p * sv) : (p * sv + r * cv);

    float ss = val * val;
    #pragma unroll
    for (int off = 1; off < 64; off <<= 1) ss += __shfl_xor(ss, off);
    float nrm = val * rsqrtf(ss * (1.0f / 64.0f) + 1e-6f);

    float wrow[8];
    *(float4*)&wrow[0] = *(const float4*)&Wd[lane * 8];
    *(float4*)&wrow[4] = *(const float4*)&Wd[lane * 8 + 4];

    float z[8];
    #pragma unroll
    for (int j = 0; j < 8; ++j) z[j] = nrm * wrow[j];
    #pragma unroll
    for (int j = 0; j < 8; ++j) {
        #pragma unroll
        for (int off = 1; off < 64; off <<= 1) z[j] += __shfl_xor(z[j], off);
    }

    if (lane == 0) {
        size_t base = ((size_t)(b * NH + h) * T_SEQ + t) * KD;
        #pragma unroll
        for (int j = 0; j < 8; ++j)
            dig[base + j] = 1.0f / (1.0f + exp2f(-LOG2E * z[j]));
    }
}

// ---------------------------------------------------------------------------
// Fused ultrametric causal attention (round-1 structure; y written as bf16).
// ---------------------------------------------------------------------------
__global__ __launch_bounds__(256)
void attn_kernel(const float* __restrict__ qdig, const float* __restrict__ kdig,
                 const float* __restrict__ vraw, u16* __restrict__ y)
{
    __shared__ float vs[64 * 64];
    __shared__ float kds[64 * 8];
    __shared__ float red[64 * 68];
    __shared__ float pden[4 * 64];

    const int tid = threadIdx.x;
    const int w = tid >> 6, lane = tid & 63;
    const int c = blockIdx.x, h = blockIdx.y, b = blockIdx.z;
    const int q = c * 64 + lane;
    const size_t bhT = (size_t)(b * NH + h) * T_SEQ;

    float qd[8];
    {
        const float* qp = qdig + (bhT + q) * KD;
        *(float4*)&qd[0] = *(const float4*)qp;
        *(float4*)&qd[4] = *(const float4*)(qp + 4);
    }

    float4 acc[16];
    #pragma unroll
    for (int u2 = 0; u2 < 16; ++u2) acc[u2] = make_float4(0.f, 0.f, 0.f, 0.f);
    float den = 0.f;

    const int ntiles = c + 1;
    for (int kt = 0; kt < ntiles; ++kt) {
        const int k0 = kt * 64;
        __syncthreads();
        {
            const int r = tid >> 2, cq = (tid & 3) * 16;
            const float* src = vraw + ((size_t)(b * T_SEQ + k0 + r)) * CDIM + h * DH + cq;
            float4* dst = (float4*)&vs[r * 64 + cq];
            #pragma unroll
            for (int u2 = 0; u2 < 4; ++u2) dst[u2] = ((const float4*)src)[u2];
            const float* ksrc = kdig + (bhT + k0) * KD;
            *(float2*)&kds[tid * 2] = *(const float2*)&ksrc[tid * 2];
        }
        __syncthreads();

        for (int j = 0; j < 16; ++j) {
            const int kl = j * 4 + w;
            const int k = k0 + kl;
            float kd[8];
            *(float4*)&kd[0] = *(const float4*)&kds[kl * 8];
            *(float4*)&kd[4] = *(const float4*)&kds[kl * 8 + 4];

            float cum = 1.f, lcp = 0.f;
            #pragma unroll
            for (int jj = 0; jj < 8; ++jj) {
                float d = qd[jj] - kd[jj];
                cum *= exp2f(-BETA_LOG2E * d * d);
                lcp += cum;
            }
            float wgt = (k <= q) ? exp2f(lcp) : 0.f;
            den += wgt;

            const float4* vrow = (const float4*)&vs[kl * 64];
            #pragma unroll
            for (int u2 = 0; u2 < 16; ++u2) {
                float4 vv = vrow[u2];
                acc[u2].x += wgt * vv.x; acc[u2].y += wgt * vv.y;
                acc[u2].z += wgt * vv.z; acc[u2].w += wgt * vv.w;
            }
        }
    }

    pden[w * 64 + lane] = den;
    for (int wv = 0; wv < 4; ++wv) {
        if (w == wv) {
            float* pb = &red[lane * 68];
            if (wv == 0) {
                #pragma unroll
                for (int u2 = 0; u2 < 16; ++u2) *(float4*)&pb[u2 * 4] = acc[u2];
            } else {
                #pragma unroll
                for (int u2 = 0; u2 < 16; ++u2) {
                    float4 t0 = *(float4*)&pb[u2 * 4];
                    t0.x += acc[u2].x; t0.y += acc[u2].y;
                    t0.z += acc[u2].z; t0.w += acc[u2].w;
                    *(float4*)&pb[u2 * 4] = t0;
                }
            }
        }
        __syncthreads();
    }

    const int qr = tid >> 2, dg = (tid & 3) * 16;
    float den4 = pden[qr] + pden[64 + qr] + pden[128 + qr] + pden[192 + qr];
    float inv = 1.f / fmaxf(den4, 1e-9f);
    const float* rb = &red[qr * 68 + dg];
    u16* yr = y + ((size_t)(b * T_SEQ + c * 64 + qr)) * CDIM + h * DH + dg;
    uint4 p0, p1;
    p0.x = f2bf(rb[0] * inv)  | ((unsigned)f2bf(rb[1] * inv)  << 16);
    p0.y = f2bf(rb[2] * inv)  | ((unsigned)f2bf(rb[3] * inv)  << 16);
    p0.z = f2bf(rb[4] * inv)  | ((unsigned)f2bf(rb[5] * inv)  << 16);
    p0.w = f2bf(rb[6] * inv)  | ((unsigned)f2bf(rb[7] * inv)  << 16);
    p1.x = f2bf(rb[8] * inv)  | ((unsigned)f2bf(rb[9] * inv)  << 16);
    p1.y = f2bf(rb[10] * inv) | ((unsigned)f2bf(rb[11] * inv) << 16);
    p1.z = f2bf(rb[12] * inv) | ((unsigned)f2bf(rb[13] * inv) << 16);
    p1.w = f2bf(rb[14] * inv) | ((unsigned)f2bf(rb[15] * inv) << 16);
    *(uint4*)(yr + 0) = p0;
    *(uint4*)(yr + 8) = p1;
}

// ---------------------------------------------------------------------------
extern "C" void kernel_launch(void* const* d_in, const int* in_sizes, int n_in,
                              void* d_out, int out_size, void* d_ws, size_t ws_size,
                              hipStream_t stream)
{
    (void)in_sizes; (void)n_in; (void)out_size; (void)ws_size;
    const float* x    = (const float*)d_in[0];
    const float* cosp = (const float*)d_in[1];
    const float* sinp = (const float*)d_in[2];
    const float* Wq   = (const float*)d_in[3];
    const float* Wk   = (const float*)d_in[4];
    const float* Wv   = (const float*)d_in[5];
    const float* Wo   = (const float*)d_in[6];
    const float* Wdq  = (const float*)d_in[7];
    const float* Wdk  = (const float*)d_in[8];
    float* out = (float*)d_out;

    const int M = BB * T_SEQ;                 // 1024
    const size_t MC = (size_t)M * CDIM;       // 1M elems
    char* p = (char*)d_ws;
    float* rawQ = (float*)p; p += MC * 4;
    float* rawK = (float*)p; p += MC * 4;
    float* rawV = (float*)p; p += MC * 4;
    float* qdig = (float*)p; p += (size_t)M * NH * KD * 4;
    float* kdig = (float*)p; p += (size_t)M * NH * KD * 4;
    u16* xb  = (u16*)p; p += MC * 2;
    u16* wqt = (u16*)p; p += MC * 2;
    u16* wkt = (u16*)p; p += MC * 2;
    u16* wvt = (u16*)p; p += MC * 2;
    u16* wot = (u16*)p; p += MC * 2;
    u16* ybuf = (u16*)p; p += MC * 2;

    dim3 blk(256);
    convert_x<<<512, blk, 0, stream>>>(x, xb);
    transpose_bf16<<<dim3(32, 32, 4), blk, 0, stream>>>(
        Wq, Wk, Wv, Wo, wqt, wkt, wvt, wot);
    gemm_bf16_multi<<<dim3(16, 16, 3), blk, 0, stream>>>(
        xb, wqt, wkt, wvt, rawQ, rawK, rawV, M, CDIM, CDIM);
    rope_digits<<<dim3(4096, 2), blk, 0, stream>>>(
        rawQ, rawK, cosp, sinp, Wdq, Wdk, qdig, kdig);
    attn_kernel<<<dim3(8, NH, BB), blk, 0, stream>>>(qdig, kdig, rawV, ybuf);
    gemm_bf16_multi<<<dim3(16, 16, 1), blk, 0, stream>>>(
        ybuf, wot, wot, wot, out, out, out, M, CDIM, CDIM);
}

// Round 3
// 99.098 us; speedup vs baseline: 2.5507x; 1.5780x over previous
//
#include <hip/hip_runtime.h>

#define T_SEQ 512
#define CDIM  1024
#define NH    16
#define DH    64
#define BB    2
#define KD    8

#define BETA_LOG2E 46.16624131f   // 32*log2(e)
#define LOG2E      1.4426950408889634f

typedef unsigned short u16;
typedef __attribute__((ext_vector_type(8))) short bf16x8;
typedef __attribute__((ext_vector_type(4))) float f32x4;

__device__ inline u16 f2bf(float f) {
    unsigned int u = __builtin_bit_cast(unsigned int, f);
    unsigned int r = (u + 0x7fffu + ((u >> 16) & 1u)) >> 16;
    return (u16)r;
}

__device__ inline void gload_lds16(const void* g, void* l) {
    __builtin_amdgcn_global_load_lds(
        (const __attribute__((address_space(1))) void*)g,
        (__attribute__((address_space(3))) void*)l, 16, 0, 0);
}

// ---------------------------------------------------------------------------
// x (fp32, row-major) -> bf16, same layout. 8 elems/thread.
// ---------------------------------------------------------------------------
__global__ __launch_bounds__(256)
void convert_x(const float* __restrict__ src, u16* __restrict__ dst)
{
    int i = (blockIdx.x * 256 + threadIdx.x) * 8;
    float4 a = *(const float4*)(src + i);
    float4 b = *(const float4*)(src + i + 4);
    uint4 p;
    p.x = f2bf(a.x) | ((unsigned)f2bf(a.y) << 16);
    p.y = f2bf(a.z) | ((unsigned)f2bf(a.w) << 16);
    p.z = f2bf(b.x) | ((unsigned)f2bf(b.y) << 16);
    p.w = f2bf(b.z) | ((unsigned)f2bf(b.w) << 16);
    *(uint4*)(dst + i) = p;
}

// ---------------------------------------------------------------------------
// W [K][N] fp32 -> Wt [N][K] bf16 (32x32 LDS tile transpose). z selects matrix.
// ---------------------------------------------------------------------------
__global__ __launch_bounds__(256)
void transpose_bf16(const float* __restrict__ W0, const float* __restrict__ W1,
                    const float* __restrict__ W2, const float* __restrict__ W3,
                    u16* __restrict__ T0, u16* __restrict__ T1,
                    u16* __restrict__ T2, u16* __restrict__ T3)
{
    __shared__ u16 tile[32][33];
    const float* W = (blockIdx.z == 0) ? W0 : (blockIdx.z == 1) ? W1
                   : (blockIdx.z == 2) ? W2 : W3;
    u16* Tt        = (blockIdx.z == 0) ? T0 : (blockIdx.z == 1) ? T1
                   : (blockIdx.z == 2) ? T2 : T3;
    const int k0 = blockIdx.y * 32, n0 = blockIdx.x * 32;
    const int r = threadIdx.x >> 3, c4 = (threadIdx.x & 7) * 4;

    float4 v = *(const float4*)&W[(size_t)(k0 + r) * CDIM + n0 + c4];
    tile[r][c4 + 0] = f2bf(v.x);
    tile[r][c4 + 1] = f2bf(v.y);
    tile[r][c4 + 2] = f2bf(v.z);
    tile[r][c4 + 3] = f2bf(v.w);
    __syncthreads();
    ushort4 o;
    o.x = tile[c4 + 0][r];
    o.y = tile[c4 + 1][r];
    o.z = tile[c4 + 2][r];
    o.w = tile[c4 + 3][r];
    *(ushort4*)&Tt[(size_t)(n0 + r) * CDIM + k0 + c4] = o;
}

// ---------------------------------------------------------------------------
// bf16 MFMA GEMM (unchanged from round 2). C(fp32) = A @ Bt^T.
// ---------------------------------------------------------------------------
__global__ __launch_bounds__(256)
void gemm_bf16_multi(const u16* __restrict__ A,
                     const u16* __restrict__ B0, const u16* __restrict__ B1,
                     const u16* __restrict__ B2,
                     float* __restrict__ C0, float* __restrict__ C1,
                     float* __restrict__ C2,
                     int M, int N, int K)
{
    __shared__ u16 As[64 * 64];
    __shared__ u16 Bs[64 * 64];

    const u16* Bt = (blockIdx.z == 0) ? B0 : (blockIdx.z == 1) ? B1 : B2;
    float*     C  = (blockIdx.z == 0) ? C0 : (blockIdx.z == 1) ? C1 : C2;

    const int tid = threadIdx.x;
    const int l = tid & 63, w = tid >> 6;
    const int m0 = blockIdx.y * 64, n0 = blockIdx.x * 64;
    const int wr = (w >> 1) * 32, wc = (w & 1) * 32;

    const int srow = l >> 3;
    const int sslot = (l & 7) ^ srow;

    f32x4 acc[2][2];
    #pragma unroll
    for (int i = 0; i < 2; ++i)
        #pragma unroll
        for (int j = 0; j < 2; ++j)
            acc[i][j] = (f32x4){0.f, 0.f, 0.f, 0.f};

    for (int k0 = 0; k0 < K; k0 += 64) {
        __syncthreads();
        #pragma unroll
        for (int q = 0; q < 2; ++q) {
            const int row = w * 16 + q * 8 + srow;
            gload_lds16(A  + (size_t)(m0 + row) * K + k0 + sslot * 8,
                        &As[(w * 16 + q * 8) * 64]);
            gload_lds16(Bt + (size_t)(n0 + row) * K + k0 + sslot * 8,
                        &Bs[(w * 16 + q * 8) * 64]);
        }
        __syncthreads();

        bf16x8 af[2][2], bf[2][2];
        #pragma unroll
        for (int i = 0; i < 2; ++i)
            #pragma unroll
            for (int kh = 0; kh < 2; ++kh) {
                const int ra = wr + i * 16 + (l & 15);
                const int sa = (kh * 4 + (l >> 4)) ^ (ra & 7);
                af[i][kh] = *(const bf16x8*)&As[ra * 64 + sa * 8];
                const int rb = wc + i * 16 + (l & 15);
                const int sb = (kh * 4 + (l >> 4)) ^ (rb & 7);
                bf[i][kh] = *(const bf16x8*)&Bs[rb * 64 + sb * 8];
            }
        #pragma unroll
        for (int kh = 0; kh < 2; ++kh)
            #pragma unroll
            for (int i = 0; i < 2; ++i)
                #pragma unroll
                for (int j = 0; j < 2; ++j)
                    acc[i][j] = __builtin_amdgcn_mfma_f32_16x16x32_bf16(
                        af[i][kh], bf[j][kh], acc[i][j], 0, 0, 0);
    }

    #pragma unroll
    for (int i = 0; i < 2; ++i)
        #pragma unroll
        for (int j = 0; j < 2; ++j) {
            const int row = m0 + wr + i * 16 + (l >> 4) * 4;
            const int col = n0 + wc + j * 16 + (l & 15);
            #pragma unroll
            for (int r = 0; r < 4; ++r)
                C[(size_t)(row + r) * N + col] = acc[i][j][r];
        }
}

// ---------------------------------------------------------------------------
// RoPE + RMS-norm + digit projection (unchanged).
// ---------------------------------------------------------------------------
__global__ __launch_bounds__(256)
void rope_digits(const float* __restrict__ rawQ, const float* __restrict__ rawK,
                 const float* __restrict__ cosp, const float* __restrict__ sinp,
                 const float* __restrict__ Wdq, const float* __restrict__ Wdk,
                 float* __restrict__ qdig, float* __restrict__ kdig)
{
    const int tid = threadIdx.x;
    const int lane = tid & 63;
    const int u = blockIdx.x * 4 + (tid >> 6);
    const int h = u & (NH - 1);
    const int m = u >> 4;
    const int t = m & (T_SEQ - 1);
    const int b = m >> 9;

    const float* raw = blockIdx.y ? rawK : rawQ;
    const float* Wd  = blockIdx.y ? Wdk  : Wdq;
    float*       dig = blockIdx.y ? kdig : qdig;

    float r = raw[(size_t)m * CDIM + h * DH + lane];
    float p = __shfl_xor(r, 32);
    const int d31 = lane & 31;
    float cv = cosp[t * 32 + d31];
    float sv = sinp[t * 32 + d31];
    float val = (lane < 32) ? (r * cv - p * sv) : (p * sv + r * cv);

    float ss = val * val;
    #pragma unroll
    for (int off = 1; off < 64; off <<= 1) ss += __shfl_xor(ss, off);
    float nrm = val * rsqrtf(ss * (1.0f / 64.0f) + 1e-6f);

    float wrow[8];
    *(float4*)&wrow[0] = *(const float4*)&Wd[lane * 8];
    *(float4*)&wrow[4] = *(const float4*)&Wd[lane * 8 + 4];

    float z[8];
    #pragma unroll
    for (int j = 0; j < 8; ++j) z[j] = nrm * wrow[j];
    #pragma unroll
    for (int j = 0; j < 8; ++j) {
        #pragma unroll
        for (int off = 1; off < 64; off <<= 1) z[j] += __shfl_xor(z[j], off);
    }

    if (lane == 0) {
        size_t base = ((size_t)(b * NH + h) * T_SEQ + t) * KD;
        #pragma unroll
        for (int j = 0; j < 8; ++j)
            dig[base + j] = 1.0f / (1.0f + exp2f(-LOG2E * z[j]));
    }
}

// ---------------------------------------------------------------------------
// Ultrametric attention, partial: ONE 64q x 64k tile per block.
// task id (blockIdx.x in [0,36)) decodes to (c, kt), kt <= c.
// Writes unnormalized partial PV (64x64 fp32) + partial denom (64 fp32).
// ---------------------------------------------------------------------------
__global__ __launch_bounds__(256)
void attn_partial(const float* __restrict__ qdig, const float* __restrict__ kdig,
                  const float* __restrict__ vraw,
                  float* __restrict__ pacc, float* __restrict__ pdeng)
{
    __shared__ float uni[64 * 68];   // V tile (stride 64) then reduce buf (stride 68)
    __shared__ float kds[64 * 8];
    __shared__ float pden[4 * 64];

    const int tid = threadIdx.x;
    const int w = tid >> 6, lane = tid & 63;
    const int h = blockIdx.y, b = blockIdx.z;

    int id = blockIdx.x, c = 0;
    while (id >= c + 1) { id -= (c + 1); ++c; }
    const int kt = id;

    const int q = c * 64 + lane;
    const int k0 = kt * 64;
    const size_t bhT = (size_t)(b * NH + h) * T_SEQ;

    float qd[8];
    {
        const float* qp = qdig + (bhT + q) * KD;
        *(float4*)&qd[0] = *(const float4*)qp;
        *(float4*)&qd[4] = *(const float4*)(qp + 4);
    }

    // stage V tile + k digits
    {
        const int r = tid >> 2, cq = (tid & 3) * 16;
        const float* src = vraw + ((size_t)(b * T_SEQ + k0 + r)) * CDIM + h * DH + cq;
        float4* dst = (float4*)&uni[r * 64 + cq];
        #pragma unroll
        for (int u2 = 0; u2 < 4; ++u2) dst[u2] = ((const float4*)src)[u2];
        const float* ksrc = kdig + (bhT + k0) * KD;
        *(float2*)&kds[tid * 2] = *(const float2*)&ksrc[tid * 2];
    }
    __syncthreads();

    float4 acc[16];
    #pragma unroll
    for (int u2 = 0; u2 < 16; ++u2) acc[u2] = make_float4(0.f, 0.f, 0.f, 0.f);
    float den = 0.f;
    const bool diag = (kt == c);

    for (int j = 0; j < 16; ++j) {
        const int kl = j * 4 + w;
        float kd[8];
        *(float4*)&kd[0] = *(const float4*)&kds[kl * 8];
        *(float4*)&kd[4] = *(const float4*)&kds[kl * 8 + 4];

        float cum = 1.f, lcp = 0.f;
        #pragma unroll
        for (int jj = 0; jj < 8; ++jj) {
            float d = qd[jj] - kd[jj];
            cum *= exp2f(-BETA_LOG2E * d * d);
            lcp += cum;
        }
        float wgt = exp2f(lcp);
        if (diag && (k0 + kl) > q) wgt = 0.f;
        den += wgt;

        const float4* vrow = (const float4*)&uni[kl * 64];
        #pragma unroll
        for (int u2 = 0; u2 < 16; ++u2) {
            float4 vv = vrow[u2];
            acc[u2].x += wgt * vv.x; acc[u2].y += wgt * vv.y;
            acc[u2].z += wgt * vv.z; acc[u2].w += wgt * vv.w;
        }
    }
    __syncthreads();   // all waves done reading V tile; uni becomes reduce buf

    pden[w * 64 + lane] = den;
    for (int wv = 0; wv < 4; ++wv) {
        if (w == wv) {
            float* pb = &uni[lane * 68];
            if (wv == 0) {
                #pragma unroll
                for (int u2 = 0; u2 < 16; ++u2) *(float4*)&pb[u2 * 4] = acc[u2];
            } else {
                #pragma unroll
                for (int u2 = 0; u2 < 16; ++u2) {
                    float4 t0 = *(float4*)&pb[u2 * 4];
                    t0.x += acc[u2].x; t0.y += acc[u2].y;
                    t0.z += acc[u2].z; t0.w += acc[u2].w;
                    *(float4*)&pb[u2 * 4] = t0;
                }
            }
        }
        __syncthreads();
    }

    const int task = (b * NH + h) * 36 + blockIdx.x;
    const int qr = tid >> 2, dg = (tid & 3) * 16;
    float* pa = pacc + (size_t)task * 4096 + qr * 64 + dg;
    #pragma unroll
    for (int u2 = 0; u2 < 4; ++u2)
        *(float4*)(pa + u2 * 4) = *(float4*)&uni[qr * 68 + dg + u2 * 4];
    if (tid < 64)
        pdeng[(size_t)task * 64 + tid] =
            pden[tid] + pden[64 + tid] + pden[128 + tid] + pden[192 + tid];
}

// ---------------------------------------------------------------------------
// Combine partials over kt, normalize, write y as bf16 (B,T,C).
// Grid (8, NH, BB): one block per (q-chunk c, h, b).
// ---------------------------------------------------------------------------
__global__ __launch_bounds__(256)
void attn_combine(const float* __restrict__ pacc, const float* __restrict__ pdeng,
                  u16* __restrict__ y)
{
    const int c = blockIdx.x, h = blockIdx.y, b = blockIdx.z;
    const int tid = threadIdx.x;
    const int r = tid >> 2, dg = (tid & 3) * 16;
    const int base = (b * NH + h) * 36 + c * (c + 1) / 2;

    float acc[16] = {};
    float den = 0.f;
    for (int kt = 0; kt <= c; ++kt) {
        const float* pa = pacc + (size_t)(base + kt) * 4096 + r * 64 + dg;
        #pragma unroll
        for (int u2 = 0; u2 < 4; ++u2) {
            float4 v = *(const float4*)(pa + u2 * 4);
            acc[u2 * 4 + 0] += v.x; acc[u2 * 4 + 1] += v.y;
            acc[u2 * 4 + 2] += v.z; acc[u2 * 4 + 3] += v.w;
        }
        den += pdeng[(size_t)(base + kt) * 64 + r];
    }
    float inv = 1.f / fmaxf(den, 1e-9f);

    u16* yr = y + ((size_t)(b * T_SEQ + c * 64 + r)) * CDIM + h * DH + dg;
    uint4 p0, p1;
    p0.x = f2bf(acc[0] * inv)  | ((unsigned)f2bf(acc[1] * inv)  << 16);
    p0.y = f2bf(acc[2] * inv)  | ((unsigned)f2bf(acc[3] * inv)  << 16);
    p0.z = f2bf(acc[4] * inv)  | ((unsigned)f2bf(acc[5] * inv)  << 16);
    p0.w = f2bf(acc[6] * inv)  | ((unsigned)f2bf(acc[7] * inv)  << 16);
    p1.x = f2bf(acc[8] * inv)  | ((unsigned)f2bf(acc[9] * inv)  << 16);
    p1.y = f2bf(acc[10] * inv) | ((unsigned)f2bf(acc[11] * inv) << 16);
    p1.z = f2bf(acc[12] * inv) | ((unsigned)f2bf(acc[13] * inv) << 16);
    p1.w = f2bf(acc[14] * inv) | ((unsigned)f2bf(acc[15] * inv) << 16);
    *(uint4*)(yr + 0) = p0;
    *(uint4*)(yr + 8) = p1;
}

// ---------------------------------------------------------------------------
extern "C" void kernel_launch(void* const* d_in, const int* in_sizes, int n_in,
                              void* d_out, int out_size, void* d_ws, size_t ws_size,
                              hipStream_t stream)
{
    (void)in_sizes; (void)n_in; (void)out_size; (void)ws_size;
    const float* x    = (const float*)d_in[0];
    const float* cosp = (const float*)d_in[1];
    const float* sinp = (const float*)d_in[2];
    const float* Wq   = (const float*)d_in[3];
    const float* Wk   = (const float*)d_in[4];
    const float* Wv   = (const float*)d_in[5];
    const float* Wo   = (const float*)d_in[6];
    const float* Wdq  = (const float*)d_in[7];
    const float* Wdk  = (const float*)d_in[8];
    float* out = (float*)d_out;

    const int M = BB * T_SEQ;                 // 1024
    const size_t MC = (size_t)M * CDIM;       // 1M elems
    char* p = (char*)d_ws;
    float* rawV = (float*)p; p += MC * 4;
    float* qdig = (float*)p; p += (size_t)M * NH * KD * 4;
    float* kdig = (float*)p; p += (size_t)M * NH * KD * 4;
    u16* xb  = (u16*)p; p += MC * 2;
    u16* wqt = (u16*)p; p += MC * 2;
    u16* wkt = (u16*)p; p += MC * 2;
    u16* wvt = (u16*)p; p += MC * 2;
    u16* wot = (u16*)p; p += MC * 2;
    u16* ybuf = (u16*)p; p += MC * 2;
    // P region: rawQ/rawK live only between QKV GEMM and rope_digits;
    // attention partials alias the same memory afterwards.
    float* rawQ  = (float*)p;
    float* rawK  = (float*)(p + MC * 4);
    float* pacc  = (float*)p;                        // 1152 * 4096 * 4 = 18.9 MB
    float* pdeng = (float*)(p + (size_t)1152 * 4096 * 4);  // 1152 * 64 * 4

    dim3 blk(256);
    convert_x<<<512, blk, 0, stream>>>(x, xb);
    transpose_bf16<<<dim3(32, 32, 4), blk, 0, stream>>>(
        Wq, Wk, Wv, Wo, wqt, wkt, wvt, wot);
    gemm_bf16_multi<<<dim3(16, 16, 3), blk, 0, stream>>>(
        xb, wqt, wkt, wvt, rawQ, rawK, rawV, M, CDIM, CDIM);
    rope_digits<<<dim3(4096, 2), blk, 0, stream>>>(
        rawQ, rawK, cosp, sinp, Wdq, Wdk, qdig, kdig);
    attn_partial<<<dim3(36, NH, BB), blk, 0, stream>>>(
        qdig, kdig, rawV, pacc, pdeng);
    attn_combine<<<dim3(8, NH, BB), blk, 0, stream>>>(pacc, pdeng, ybuf);
    gemm_bf16_multi<<<dim3(16, 16, 1), blk, 0, stream>>>(
        ybuf, wot, wot, wot, out, out, out, M, CDIM, CDIM);
}

// Round 4
// 79.705 us; speedup vs baseline: 3.1714x; 1.2433x over previous
//
#include <hip/hip_runtime.h>

#define T_SEQ 512
#define CDIM  1024
#define NH    16
#define DH    64
#define BB    2
#define KD    8

#define BETA_LOG2E 46.16624131f   // 32*log2(e)
#define LOG2E      1.4426950408889634f

typedef unsigned short u16;
typedef __attribute__((ext_vector_type(8))) short bf16x8;
typedef __attribute__((ext_vector_type(4))) float f32x4;

__device__ inline u16 f2bf(float f) {
    unsigned int u = __builtin_bit_cast(unsigned int, f);
    unsigned int r = (u + 0x7fffu + ((u >> 16) & 1u)) >> 16;
    return (u16)r;
}

__device__ inline void gload_lds16(const void* g, void* l) {
    __builtin_amdgcn_global_load_lds(
        (const __attribute__((address_space(1))) void*)g,
        (__attribute__((address_space(3))) void*)l, 16, 0, 0);
}

// ---------------------------------------------------------------------------
// Prep: z=0..3 -> transpose W to bf16 [N][K]; z=4 -> convert x to bf16.
// ---------------------------------------------------------------------------
__global__ __launch_bounds__(256)
void prep_kernel(const float* __restrict__ x,
                 const float* __restrict__ W0, const float* __restrict__ W1,
                 const float* __restrict__ W2, const float* __restrict__ W3,
                 u16* __restrict__ xb,
                 u16* __restrict__ T0, u16* __restrict__ T1,
                 u16* __restrict__ T2, u16* __restrict__ T3)
{
    const int tid = threadIdx.x;
    if (blockIdx.z == 4) {
        const int row = blockIdx.y * 32 + (tid >> 3);
        const int col = blockIdx.x * 32 + (tid & 7) * 4;
        float4 v = *(const float4*)&x[(size_t)row * CDIM + col];
        ushort4 o = { f2bf(v.x), f2bf(v.y), f2bf(v.z), f2bf(v.w) };
        *(ushort4*)&xb[(size_t)row * CDIM + col] = o;
        return;
    }
    __shared__ u16 tile[32][33];
    const float* W = (blockIdx.z == 0) ? W0 : (blockIdx.z == 1) ? W1
                   : (blockIdx.z == 2) ? W2 : W3;
    u16* Tt        = (blockIdx.z == 0) ? T0 : (blockIdx.z == 1) ? T1
                   : (blockIdx.z == 2) ? T2 : T3;
    const int k0 = blockIdx.y * 32, n0 = blockIdx.x * 32;
    const int r = tid >> 3, c4 = (tid & 7) * 4;

    float4 v = *(const float4*)&W[(size_t)(k0 + r) * CDIM + n0 + c4];
    tile[r][c4 + 0] = f2bf(v.x);
    tile[r][c4 + 1] = f2bf(v.y);
    tile[r][c4 + 2] = f2bf(v.z);
    tile[r][c4 + 3] = f2bf(v.w);
    __syncthreads();
    ushort4 o;
    o.x = tile[c4 + 0][r];
    o.y = tile[c4 + 1][r];
    o.z = tile[c4 + 2][r];
    o.w = tile[c4 + 3][r];
    *(ushort4*)&Tt[(size_t)(n0 + r) * CDIM + k0 + c4] = o;
}

// ---------------------------------------------------------------------------
// Fused QKV GEMM. 64x64 tile, BK=64, 4 waves of 32x32. n-tile == head.
// z=0 (Q) / z=1 (K): epilogue does RoPE + RMS-norm + digit projection,
//   writing ONLY the 8 sigmoid digits per (b,h,t). No C written to HBM.
// z=2 (V): epilogue writes V^T as bf16, layout [b][h][d][t].
// ---------------------------------------------------------------------------
__global__ __launch_bounds__(256)
void gemm_qkv_fused(const u16* __restrict__ A,
                    const u16* __restrict__ Bq, const u16* __restrict__ Bk,
                    const u16* __restrict__ Bv,
                    const float* __restrict__ cosp, const float* __restrict__ sinp,
                    const float* __restrict__ Wdq, const float* __restrict__ Wdk,
                    float* __restrict__ qdig, float* __restrict__ kdig,
                    u16* __restrict__ Vt)
{
    __shared__ __align__(16) char smem[64 * 65 * 4];   // staging (16KB) / Cf f32
    u16* As = (u16*)smem;
    u16* Bs = As + 4096;
    float* Cf = (float*)smem;    // [64][65] after MFMA phase

    const int z = blockIdx.z;
    const u16* Bt = (z == 0) ? Bq : (z == 1) ? Bk : Bv;

    const int tid = threadIdx.x;
    const int l = tid & 63, w = tid >> 6;
    const int m0 = blockIdx.y * 64;
    const int h  = blockIdx.x;               // n-tile == head
    const int n0 = h * 64;
    const int wr = (w >> 1) * 32, wc = (w & 1) * 32;

    const int srow = l >> 3;
    const int sslot = (l & 7) ^ srow;

    f32x4 acc[2][2];
    #pragma unroll
    for (int i = 0; i < 2; ++i)
        #pragma unroll
        for (int j = 0; j < 2; ++j)
            acc[i][j] = (f32x4){0.f, 0.f, 0.f, 0.f};

    for (int k0 = 0; k0 < CDIM; k0 += 64) {
        __syncthreads();
        #pragma unroll
        for (int q = 0; q < 2; ++q) {
            const int row = w * 16 + q * 8 + srow;
            gload_lds16(A  + (size_t)(m0 + row) * CDIM + k0 + sslot * 8,
                        &As[(w * 16 + q * 8) * 64]);
            gload_lds16(Bt + (size_t)(n0 + row) * CDIM + k0 + sslot * 8,
                        &Bs[(w * 16 + q * 8) * 64]);
        }
        __syncthreads();

        bf16x8 af[2][2], bfr[2][2];
        #pragma unroll
        for (int i = 0; i < 2; ++i)
            #pragma unroll
            for (int kh = 0; kh < 2; ++kh) {
                const int ra = wr + i * 16 + (l & 15);
                const int sa = (kh * 4 + (l >> 4)) ^ (ra & 7);
                af[i][kh] = *(const bf16x8*)&As[ra * 64 + sa * 8];
                const int rb = wc + i * 16 + (l & 15);
                const int sb = (kh * 4 + (l >> 4)) ^ (rb & 7);
                bfr[i][kh] = *(const bf16x8*)&Bs[rb * 64 + sb * 8];
            }
        #pragma unroll
        for (int kh = 0; kh < 2; ++kh)
            #pragma unroll
            for (int i = 0; i < 2; ++i)
                #pragma unroll
                for (int j = 0; j < 2; ++j)
                    acc[i][j] = __builtin_amdgcn_mfma_f32_16x16x32_bf16(
                        af[i][kh], bfr[j][kh], acc[i][j], 0, 0, 0);
    }

    __syncthreads();   // staging reads done; smem becomes Cf

    if (z == 2) {
        // write acc TRANSPOSED into LDS: Cf[d][m], stride 65
        #pragma unroll
        for (int i = 0; i < 2; ++i)
            #pragma unroll
            for (int j = 0; j < 2; ++j) {
                const int mm = wr + i * 16 + (l >> 4) * 4;
                const int dd = wc + j * 16 + (l & 15);
                #pragma unroll
                for (int r = 0; r < 4; ++r)
                    Cf[dd * 65 + mm + r] = acc[i][j][r];
            }
        __syncthreads();
        const int b = m0 >> 9, t0 = m0 & (T_SEQ - 1);
        u16* vbase = Vt + ((size_t)(b * NH + h) * 64) * T_SEQ;
        #pragma unroll
        for (int it = 0; it < 16; ++it) {
            const int d = it * 4 + w;
            vbase[(size_t)d * T_SEQ + t0 + l] = f2bf(Cf[d * 65 + l]);
        }
        return;
    }

    // Q/K path: Cf[m][d], stride 65
    #pragma unroll
    for (int i = 0; i < 2; ++i)
        #pragma unroll
        for (int j = 0; j < 2; ++j) {
            const int mm = wr + i * 16 + (l >> 4) * 4;
            const int dd = wc + j * 16 + (l & 15);
            #pragma unroll
            for (int r = 0; r < 4; ++r)
                Cf[(mm + r) * 65 + dd] = acc[i][j][r];
        }

    const float* Wd = z ? Wdk : Wdq;
    float* dig = z ? kdig : qdig;
    float wrow[8];
    *(float4*)&wrow[0] = *(const float4*)&Wd[l * 8];
    *(float4*)&wrow[4] = *(const float4*)&Wd[l * 8 + 4];
    __syncthreads();

    // wave w processes rows w*16 .. w*16+15; lane = d
    for (int qi = 0; qi < 16; ++qi) {
        const int m = w * 16 + qi;
        const int mg = m0 + m;
        const int b = mg >> 9, t = mg & (T_SEQ - 1);

        float r = Cf[m * 65 + l];
        float p = Cf[m * 65 + (l ^ 32)];
        float cv = cosp[t * 32 + (l & 31)];
        float sv = sinp[t * 32 + (l & 31)];
        float val = (l < 32) ? (r * cv - p * sv) : (p * sv + r * cv);

        float ss = val * val;
        #pragma unroll
        for (int off = 1; off < 64; off <<= 1) ss += __shfl_xor(ss, off);
        float nrm = val * rsqrtf(ss * (1.0f / 64.0f) + 1e-6f);

        float zz[8];
        #pragma unroll
        for (int j = 0; j < 8; ++j) zz[j] = nrm * wrow[j];
        #pragma unroll
        for (int j = 0; j < 8; ++j) {
            #pragma unroll
            for (int off = 1; off < 64; off <<= 1) zz[j] += __shfl_xor(zz[j], off);
        }
        // lanes 0..7 each store one digit (select chain keeps indices static)
        float zsel = zz[0];
        #pragma unroll
        for (int j = 1; j < 8; ++j) zsel = (l == j) ? zz[j] : zsel;
        if (l < 8) {
            size_t base = ((size_t)(b * NH + h) * T_SEQ + t) * KD;
            dig[base + l] = 1.0f / (1.0f + exp2f(-LOG2E * zsel));
        }
    }
}

// ---------------------------------------------------------------------------
// Ultrametric attention partial, MFMA version. One 64q x 64k tile per block.
// lane = k computes bf16 weights into swizzled LDS; PV + denominator via
// mfma_f32_16x16x32_bf16 (denominator through a ones-B-operand MFMA).
// ---------------------------------------------------------------------------
__global__ __launch_bounds__(256)
void attn_partial(const float* __restrict__ qdig, const float* __restrict__ kdig,
                  const u16* __restrict__ Vt,
                  float* __restrict__ pacc, float* __restrict__ pdeng)
{
    __shared__ u16 Vs[4096];    // [d][k] swizzled, 8KB
    __shared__ u16 Ps[4096];    // [q][k] swizzled, 8KB
    __shared__ float qds[512];  // [q][8]

    const int tid = threadIdx.x;
    const int w = tid >> 6, l = tid & 63;
    const int h = blockIdx.y, b = blockIdx.z;
    const int bh = b * NH + h;
    const size_t bhT = (size_t)bh * T_SEQ;

    int id = blockIdx.x, c = 0;
    while (id >= c + 1) { id -= (c + 1); ++c; }
    const int kt = id;
    const int k0 = kt * 64;

    // stage V^T rows [d][k0..k0+64) with XOR swizzle on source slot
    const int srow = l >> 3, sslot = (l & 7) ^ srow;
    #pragma unroll
    for (int q2 = 0; q2 < 2; ++q2) {
        const int R0 = w * 16 + q2 * 8;
        gload_lds16(Vt + ((size_t)bh * 64 + R0 + srow) * T_SEQ + k0 + sslot * 8,
                    &Vs[R0 * 64]);
    }
    *(float2*)&qds[tid * 2] = *(const float2*)&qdig[(bhT + c * 64) * KD + tid * 2];

    float kd[8];
    {
        const float* kp = &kdig[(bhT + k0 + l) * KD];
        *(float4*)&kd[0] = *(const float4*)kp;
        *(float4*)&kd[4] = *(const float4*)(kp + 4);
    }
    __syncthreads();

    // P compute: wave w -> q rows [w*16, w*16+16), lane = k
    const bool diag = (kt == c);
    for (int qi = 0; qi < 16; ++qi) {
        const int qrow = w * 16 + qi;
        float qd[8];
        *(float4*)&qd[0] = *(const float4*)&qds[qrow * 8];
        *(float4*)&qd[4] = *(const float4*)&qds[qrow * 8 + 4];
        float cum = 1.f, lcp = 0.f;
        #pragma unroll
        for (int jj = 0; jj < 8; ++jj) {
            float d = qd[jj] - kd[jj];
            cum *= exp2f(-BETA_LOG2E * d * d);
            lcp += cum;
        }
        float wgt = exp2f(lcp);
        if (diag && l > qrow) wgt = 0.f;
        Ps[qrow * 64 + (((l >> 3) ^ (qi & 7)) << 3) + (l & 7)] = f2bf(wgt);
    }
    __syncthreads();

    // PV + denom via MFMA; wave w owns output quadrant (wr, wc)
    const int wr = (w >> 1) * 32, wc = (w & 1) * 32;
    f32x4 acc[2][2], accd[2];
    #pragma unroll
    for (int i = 0; i < 2; ++i) {
        accd[i] = (f32x4){0.f, 0.f, 0.f, 0.f};
        #pragma unroll
        for (int j = 0; j < 2; ++j) acc[i][j] = (f32x4){0.f, 0.f, 0.f, 0.f};
    }
    bf16x8 ones;
    #pragma unroll
    for (int i = 0; i < 8; ++i) ones[i] = (short)0x3F80;

    #pragma unroll
    for (int kh = 0; kh < 2; ++kh) {
        bf16x8 af[2], bfr[2];
        #pragma unroll
        for (int i = 0; i < 2; ++i) {
            const int ra = wr + i * 16 + (l & 15);
            const int sa = (kh * 4 + (l >> 4)) ^ (ra & 7);
            af[i] = *(const bf16x8*)&Ps[ra * 64 + sa * 8];
            const int rb = wc + i * 16 + (l & 15);
            const int sb = (kh * 4 + (l >> 4)) ^ (rb & 7);
            bfr[i] = *(const bf16x8*)&Vs[rb * 64 + sb * 8];
        }
        #pragma unroll
        for (int i = 0; i < 2; ++i) {
            accd[i] = __builtin_amdgcn_mfma_f32_16x16x32_bf16(af[i], ones, accd[i], 0, 0, 0);
            #pragma unroll
            for (int j = 0; j < 2; ++j)
                acc[i][j] = __builtin_amdgcn_mfma_f32_16x16x32_bf16(
                    af[i], bfr[j], acc[i][j], 0, 0, 0);
        }
    }

    const int task = bh * 36 + blockIdx.x;
    float* pa = pacc + (size_t)task * 4096;
    #pragma unroll
    for (int i = 0; i < 2; ++i) {
        const int row = wr + i * 16 + (l >> 4) * 4;
        #pragma unroll
        for (int j = 0; j < 2; ++j) {
            const int col = wc + j * 16 + (l & 15);
            #pragma unroll
            for (int r = 0; r < 4; ++r)
                pa[(size_t)(row + r) * 64 + col] = acc[i][j][r];
        }
        if ((l & 15) == 0) {
            #pragma unroll
            for (int r = 0; r < 4; ++r)
                pdeng[(size_t)task * 64 + row + r] = accd[i][r];
        }
    }
}

// ---------------------------------------------------------------------------
// Combine partials over kt, normalize, write y as bf16 (B,T,C).
// ---------------------------------------------------------------------------
__global__ __launch_bounds__(256)
void attn_combine(const float* __restrict__ pacc, const float* __restrict__ pdeng,
                  u16* __restrict__ y)
{
    const int c = blockIdx.x, h = blockIdx.y, b = blockIdx.z;
    const int tid = threadIdx.x;
    const int r = tid >> 2, dg = (tid & 3) * 16;
    const int base = (b * NH + h) * 36 + c * (c + 1) / 2;

    float acc[16] = {};
    float den = 0.f;
    for (int kt = 0; kt <= c; ++kt) {
        const float* pa = pacc + (size_t)(base + kt) * 4096 + r * 64 + dg;
        #pragma unroll
        for (int u2 = 0; u2 < 4; ++u2) {
            float4 v = *(const float4*)(pa + u2 * 4);
            acc[u2 * 4 + 0] += v.x; acc[u2 * 4 + 1] += v.y;
            acc[u2 * 4 + 2] += v.z; acc[u2 * 4 + 3] += v.w;
        }
        den += pdeng[(size_t)(base + kt) * 64 + r];
    }
    float inv = 1.f / fmaxf(den, 1e-9f);

    u16* yr = y + ((size_t)(b * T_SEQ + c * 64 + r)) * CDIM + h * DH + dg;
    uint4 p0, p1;
    p0.x = f2bf(acc[0] * inv)  | ((unsigned)f2bf(acc[1] * inv)  << 16);
    p0.y = f2bf(acc[2] * inv)  | ((unsigned)f2bf(acc[3] * inv)  << 16);
    p0.z = f2bf(acc[4] * inv)  | ((unsigned)f2bf(acc[5] * inv)  << 16);
    p0.w = f2bf(acc[6] * inv)  | ((unsigned)f2bf(acc[7] * inv)  << 16);
    p1.x = f2bf(acc[8] * inv)  | ((unsigned)f2bf(acc[9] * inv)  << 16);
    p1.y = f2bf(acc[10] * inv) | ((unsigned)f2bf(acc[11] * inv) << 16);
    p1.z = f2bf(acc[12] * inv) | ((unsigned)f2bf(acc[13] * inv) << 16);
    p1.w = f2bf(acc[14] * inv) | ((unsigned)f2bf(acc[15] * inv) << 16);
    *(uint4*)(yr + 0) = p0;
    *(uint4*)(yr + 8) = p1;
}

// ---------------------------------------------------------------------------
// Plain bf16 MFMA GEMM for the output projection (C fp32 = A @ Bt^T).
// ---------------------------------------------------------------------------
__global__ __launch_bounds__(256)
void gemm_proj(const u16* __restrict__ A, const u16* __restrict__ Bt,
               float* __restrict__ C)
{
    __shared__ u16 As[64 * 64];
    __shared__ u16 Bs[64 * 64];

    const int tid = threadIdx.x;
    const int l = tid & 63, w = tid >> 6;
    const int m0 = blockIdx.y * 64, n0 = blockIdx.x * 64;
    const int wr = (w >> 1) * 32, wc = (w & 1) * 32;
    const int srow = l >> 3;
    const int sslot = (l & 7) ^ srow;

    f32x4 acc[2][2];
    #pragma unroll
    for (int i = 0; i < 2; ++i)
        #pragma unroll
        for (int j = 0; j < 2; ++j)
            acc[i][j] = (f32x4){0.f, 0.f, 0.f, 0.f};

    for (int k0 = 0; k0 < CDIM; k0 += 64) {
        __syncthreads();
        #pragma unroll
        for (int q = 0; q < 2; ++q) {
            const int row = w * 16 + q * 8 + srow;
            gload_lds16(A  + (size_t)(m0 + row) * CDIM + k0 + sslot * 8,
                        &As[(w * 16 + q * 8) * 64]);
            gload_lds16(Bt + (size_t)(n0 + row) * CDIM + k0 + sslot * 8,
                        &Bs[(w * 16 + q * 8) * 64]);
        }
        __syncthreads();

        bf16x8 af[2][2], bfr[2][2];
        #pragma unroll
        for (int i = 0; i < 2; ++i)
            #pragma unroll
            for (int kh = 0; kh < 2; ++kh) {
                const int ra = wr + i * 16 + (l & 15);
                const int sa = (kh * 4 + (l >> 4)) ^ (ra & 7);
                af[i][kh] = *(const bf16x8*)&As[ra * 64 + sa * 8];
                const int rb = wc + i * 16 + (l & 15);
                const int sb = (kh * 4 + (l >> 4)) ^ (rb & 7);
                bfr[i][kh] = *(const bf16x8*)&Bs[rb * 64 + sb * 8];
            }
        #pragma unroll
        for (int kh = 0; kh < 2; ++kh)
            #pragma unroll
            for (int i = 0; i < 2; ++i)
                #pragma unroll
                for (int j = 0; j < 2; ++j)
                    acc[i][j] = __builtin_amdgcn_mfma_f32_16x16x32_bf16(
                        af[i][kh], bfr[j][kh], acc[i][j], 0, 0, 0);
    }

    #pragma unroll
    for (int i = 0; i < 2; ++i)
        #pragma unroll
        for (int j = 0; j < 2; ++j) {
            const int row = m0 + wr + i * 16 + (l >> 4) * 4;
            const int col = n0 + wc + j * 16 + (l & 15);
            #pragma unroll
            for (int r = 0; r < 4; ++r)
                C[(size_t)(row + r) * CDIM + col] = acc[i][j][r];
        }
}

// ---------------------------------------------------------------------------
extern "C" void kernel_launch(void* const* d_in, const int* in_sizes, int n_in,
                              void* d_out, int out_size, void* d_ws, size_t ws_size,
                              hipStream_t stream)
{
    (void)in_sizes; (void)n_in; (void)out_size; (void)ws_size;
    const float* x    = (const float*)d_in[0];
    const float* cosp = (const float*)d_in[1];
    const float* sinp = (const float*)d_in[2];
    const float* Wq   = (const float*)d_in[3];
    const float* Wk   = (const float*)d_in[4];
    const float* Wv   = (const float*)d_in[5];
    const float* Wo   = (const float*)d_in[6];
    const float* Wdq  = (const float*)d_in[7];
    const float* Wdk  = (const float*)d_in[8];
    float* out = (float*)d_out;

    const int M = BB * T_SEQ;                 // 1024
    const size_t MC = (size_t)M * CDIM;       // 1M elems
    char* p = (char*)d_ws;
    float* qdig = (float*)p; p += (size_t)M * NH * KD * 4;   // 512KB
    float* kdig = (float*)p; p += (size_t)M * NH * KD * 4;   // 512KB
    u16* xb   = (u16*)p; p += MC * 2;
    u16* wqt  = (u16*)p; p += MC * 2;
    u16* wkt  = (u16*)p; p += MC * 2;
    u16* wvt  = (u16*)p; p += MC * 2;
    u16* wot  = (u16*)p; p += MC * 2;
    u16* Vt   = (u16*)p; p += MC * 2;         // [b][h][d][t] bf16, 2MB
    u16* ybuf = (u16*)p; p += MC * 2;
    float* pacc  = (float*)p; p += (size_t)1152 * 4096 * 4;  // 18.9MB
    float* pdeng = (float*)p; p += (size_t)1152 * 64 * 4;

    dim3 blk(256);
    prep_kernel<<<dim3(32, 32, 5), blk, 0, stream>>>(
        x, Wq, Wk, Wv, Wo, xb, wqt, wkt, wvt, wot);
    gemm_qkv_fused<<<dim3(16, 16, 3), blk, 0, stream>>>(
        xb, wqt, wkt, wvt, cosp, sinp, Wdq, Wdk, qdig, kdig, Vt);
    attn_partial<<<dim3(36, NH, BB), blk, 0, stream>>>(
        qdig, kdig, Vt, pacc, pdeng);
    attn_combine<<<dim3(8, NH, BB), blk, 0, stream>>>(pacc, pdeng, ybuf);
    gemm_proj<<<dim3(16, 16), blk, 0, stream>>>(ybuf, wot, out);
}

// Round 5
// 59.405 us; speedup vs baseline: 4.2551x; 1.3417x over previous
//
#include <hip/hip_runtime.h>

#define T_SEQ 512
#define CDIM  1024
#define NH    16
#define DH    64
#define BB    2
#define KD    8

#define BETA_LOG2E 46.16624131f   // 32*log2(e)
#define LOG2E      1.4426950408889634f

typedef unsigned short u16;
typedef __attribute__((ext_vector_type(8))) short bf16x8;
typedef __attribute__((ext_vector_type(4))) float f32x4;

__device__ inline u16 f2bf(float f) {
    unsigned int u = __builtin_bit_cast(unsigned int, f);
    unsigned int r = (u + 0x7fffu + ((u >> 16) & 1u)) >> 16;
    return (u16)r;
}
__device__ inline float bf2f(u16 v) {
    unsigned int u = ((unsigned int)v) << 16;
    return __builtin_bit_cast(float, u);
}

__device__ inline void gload_lds16(const void* g, void* l) {
    __builtin_amdgcn_global_load_lds(
        (const __attribute__((address_space(1))) void*)g,
        (__attribute__((address_space(3))) void*)l, 16, 0, 0);
}

// ---------------------------------------------------------------------------
// Prep: z=0..3 -> transpose W to bf16 [N][K]; z=4 -> convert x to bf16.
// ---------------------------------------------------------------------------
__global__ __launch_bounds__(256)
void prep_kernel(const float* __restrict__ x,
                 const float* __restrict__ W0, const float* __restrict__ W1,
                 const float* __restrict__ W2, const float* __restrict__ W3,
                 u16* __restrict__ xb,
                 u16* __restrict__ T0, u16* __restrict__ T1,
                 u16* __restrict__ T2, u16* __restrict__ T3)
{
    const int tid = threadIdx.x;
    if (blockIdx.z == 4) {
        const int row = blockIdx.y * 32 + (tid >> 3);
        const int col = blockIdx.x * 32 + (tid & 7) * 4;
        float4 v = *(const float4*)&x[(size_t)row * CDIM + col];
        ushort4 o = { f2bf(v.x), f2bf(v.y), f2bf(v.z), f2bf(v.w) };
        *(ushort4*)&xb[(size_t)row * CDIM + col] = o;
        return;
    }
    __shared__ u16 tile[32][33];
    const float* W = (blockIdx.z == 0) ? W0 : (blockIdx.z == 1) ? W1
                   : (blockIdx.z == 2) ? W2 : W3;
    u16* Tt        = (blockIdx.z == 0) ? T0 : (blockIdx.z == 1) ? T1
                   : (blockIdx.z == 2) ? T2 : T3;
    const int k0 = blockIdx.y * 32, n0 = blockIdx.x * 32;
    const int r = tid >> 3, c4 = (tid & 7) * 4;

    float4 v = *(const float4*)&W[(size_t)(k0 + r) * CDIM + n0 + c4];
    tile[r][c4 + 0] = f2bf(v.x);
    tile[r][c4 + 1] = f2bf(v.y);
    tile[r][c4 + 2] = f2bf(v.z);
    tile[r][c4 + 3] = f2bf(v.w);
    __syncthreads();
    ushort4 o;
    o.x = tile[c4 + 0][r];
    o.y = tile[c4 + 1][r];
    o.z = tile[c4 + 2][r];
    o.w = tile[c4 + 3][r];
    *(ushort4*)&Tt[(size_t)(n0 + r) * CDIM + k0 + c4] = o;
}

// ---------------------------------------------------------------------------
// Fused QKV GEMM. 64x64 tile, BK=64, 4 waves of 32x32. n-tile == head.
// z=0 (Q) / z=1 (K): epilogue does RoPE + RMS-norm + digit projection with
//   4-rows-parallel 16-lane-group reductions (RoPE pair is in-lane).
// z=2 (V): epilogue writes V^T as bf16, layout [b][h][d][t].
// ---------------------------------------------------------------------------
__global__ __launch_bounds__(256)
void gemm_qkv_fused(const u16* __restrict__ A,
                    const u16* __restrict__ Bq, const u16* __restrict__ Bk,
                    const u16* __restrict__ Bv,
                    const float* __restrict__ cosp, const float* __restrict__ sinp,
                    const float* __restrict__ Wdq, const float* __restrict__ Wdk,
                    float* __restrict__ qdig, float* __restrict__ kdig,
                    u16* __restrict__ Vt)
{
    __shared__ __align__(16) char smem[64 * 65 * 4];   // staging (16KB) / Cf f32
    u16* As = (u16*)smem;
    u16* Bs = As + 4096;
    float* Cf = (float*)smem;    // [64][65] after MFMA phase

    const int z = blockIdx.z;
    const u16* Bt = (z == 0) ? Bq : (z == 1) ? Bk : Bv;

    const int tid = threadIdx.x;
    const int l = tid & 63, w = tid >> 6;
    const int m0 = blockIdx.y * 64;
    const int h  = blockIdx.x;               // n-tile == head
    const int n0 = h * 64;
    const int wr = (w >> 1) * 32, wc = (w & 1) * 32;

    const int srow = l >> 3;
    const int sslot = (l & 7) ^ srow;

    f32x4 acc[2][2];
    #pragma unroll
    for (int i = 0; i < 2; ++i)
        #pragma unroll
        for (int j = 0; j < 2; ++j)
            acc[i][j] = (f32x4){0.f, 0.f, 0.f, 0.f};

    for (int k0 = 0; k0 < CDIM; k0 += 64) {
        __syncthreads();
        #pragma unroll
        for (int q = 0; q < 2; ++q) {
            const int row = w * 16 + q * 8 + srow;
            gload_lds16(A  + (size_t)(m0 + row) * CDIM + k0 + sslot * 8,
                        &As[(w * 16 + q * 8) * 64]);
            gload_lds16(Bt + (size_t)(n0 + row) * CDIM + k0 + sslot * 8,
                        &Bs[(w * 16 + q * 8) * 64]);
        }
        __syncthreads();

        bf16x8 af[2][2], bfr[2][2];
        #pragma unroll
        for (int i = 0; i < 2; ++i)
            #pragma unroll
            for (int kh = 0; kh < 2; ++kh) {
                const int ra = wr + i * 16 + (l & 15);
                const int sa = (kh * 4 + (l >> 4)) ^ (ra & 7);
                af[i][kh] = *(const bf16x8*)&As[ra * 64 + sa * 8];
                const int rb = wc + i * 16 + (l & 15);
                const int sb = (kh * 4 + (l >> 4)) ^ (rb & 7);
                bfr[i][kh] = *(const bf16x8*)&Bs[rb * 64 + sb * 8];
            }
        #pragma unroll
        for (int kh = 0; kh < 2; ++kh)
            #pragma unroll
            for (int i = 0; i < 2; ++i)
                #pragma unroll
                for (int j = 0; j < 2; ++j)
                    acc[i][j] = __builtin_amdgcn_mfma_f32_16x16x32_bf16(
                        af[i][kh], bfr[j][kh], acc[i][j], 0, 0, 0);
    }

    __syncthreads();   // staging reads done; smem becomes Cf

    if (z == 2) {
        // write acc TRANSPOSED into LDS: Cf[d][m], stride 65
        #pragma unroll
        for (int i = 0; i < 2; ++i)
            #pragma unroll
            for (int j = 0; j < 2; ++j) {
                const int mm = wr + i * 16 + (l >> 4) * 4;
                const int dd = wc + j * 16 + (l & 15);
                #pragma unroll
                for (int r = 0; r < 4; ++r)
                    Cf[dd * 65 + mm + r] = acc[i][j][r];
            }
        __syncthreads();
        const int b = m0 >> 9, t0 = m0 & (T_SEQ - 1);
        u16* vbase = Vt + ((size_t)(b * NH + h) * 64) * T_SEQ;
        #pragma unroll
        for (int it = 0; it < 16; ++it) {
            const int d = it * 4 + w;
            vbase[(size_t)d * T_SEQ + t0 + l] = f2bf(Cf[d * 65 + l]);
        }
        return;
    }

    // Q/K path: Cf[m][d], stride 65
    #pragma unroll
    for (int i = 0; i < 2; ++i)
        #pragma unroll
        for (int j = 0; j < 2; ++j) {
            const int mm = wr + i * 16 + (l >> 4) * 4;
            const int dd = wc + j * 16 + (l & 15);
            #pragma unroll
            for (int r = 0; r < 4; ++r)
                Cf[(mm + r) * 65 + dd] = acc[i][j][r];
        }

    const float* Wd = z ? Wdk : Wdq;
    float* dig = z ? kdig : qdig;

    // lane = (rq = l>>4 : row-in-group, dl = l&15 : dim-low)
    const int dl = l & 15, rq = l >> 4;
    float wreg[4][8];   // Wd rows dl, dl+16, dl+32, dl+48
    #pragma unroll
    for (int d4 = 0; d4 < 4; ++d4) {
        *(float4*)&wreg[d4][0] = *(const float4*)&Wd[(dl + d4 * 16) * 8];
        *(float4*)&wreg[d4][4] = *(const float4*)&Wd[(dl + d4 * 16) * 8 + 4];
    }
    __syncthreads();

    for (int g = 0; g < 4; ++g) {
        const int m = w * 16 + g * 4 + rq;
        const int mg = m0 + m;
        const int b = mg >> 9, t = mg & (T_SEQ - 1);

        const float* cr = &Cf[m * 65];
        float r0 = cr[dl], r1 = cr[dl + 16], r2 = cr[dl + 32], r3 = cr[dl + 48];
        float c0 = cosp[t * 32 + dl], c1 = cosp[t * 32 + dl + 16];
        float s0 = sinp[t * 32 + dl], s1 = sinp[t * 32 + dl + 16];
        float v0 = r0 * c0 - r2 * s0;
        float v1 = r1 * c1 - r3 * s1;
        float v2 = r0 * s0 + r2 * c0;
        float v3 = r1 * s1 + r3 * c1;

        float ss = v0 * v0 + v1 * v1 + v2 * v2 + v3 * v3;
        #pragma unroll
        for (int off = 1; off < 16; off <<= 1) ss += __shfl_xor(ss, off);
        float sc = rsqrtf(ss * (1.0f / 64.0f) + 1e-6f);
        v0 *= sc; v1 *= sc; v2 *= sc; v3 *= sc;

        float zz[8];
        #pragma unroll
        for (int j = 0; j < 8; ++j)
            zz[j] = v0 * wreg[0][j] + v1 * wreg[1][j] + v2 * wreg[2][j] + v3 * wreg[3][j];
        #pragma unroll
        for (int j = 0; j < 8; ++j) {
            #pragma unroll
            for (int off = 1; off < 16; off <<= 1) zz[j] += __shfl_xor(zz[j], off);
        }
        float zsel = zz[0];
        #pragma unroll
        for (int j = 1; j < 8; ++j) zsel = (dl == j) ? zz[j] : zsel;
        if (dl < 8)
            dig[((size_t)(b * NH + h) * T_SEQ + t) * KD + dl] =
                1.0f / (1.0f + exp2f(-LOG2E * zsel));
    }
}

// ---------------------------------------------------------------------------
// Ultrametric attention partial (MFMA). One 64q x 64k tile per block.
// Partial PV written as bf16; partial denom fp32.
// ---------------------------------------------------------------------------
__global__ __launch_bounds__(256)
void attn_partial(const float* __restrict__ qdig, const float* __restrict__ kdig,
                  const u16* __restrict__ Vt,
                  u16* __restrict__ pacc, float* __restrict__ pdeng)
{
    __shared__ u16 Vs[4096];    // [d][k] swizzled, 8KB
    __shared__ u16 Ps[4096];    // [q][k] swizzled, 8KB
    __shared__ float qds[512];  // [q][8]

    const int tid = threadIdx.x;
    const int w = tid >> 6, l = tid & 63;
    const int h = blockIdx.y, b = blockIdx.z;
    const int bh = b * NH + h;
    const size_t bhT = (size_t)bh * T_SEQ;

    int id = blockIdx.x, c = 0;
    while (id >= c + 1) { id -= (c + 1); ++c; }
    const int kt = id;
    const int k0 = kt * 64;

    const int srow = l >> 3, sslot = (l & 7) ^ srow;
    #pragma unroll
    for (int q2 = 0; q2 < 2; ++q2) {
        const int R0 = w * 16 + q2 * 8;
        gload_lds16(Vt + ((size_t)bh * 64 + R0 + srow) * T_SEQ + k0 + sslot * 8,
                    &Vs[R0 * 64]);
    }
    *(float2*)&qds[tid * 2] = *(const float2*)&qdig[(bhT + c * 64) * KD + tid * 2];

    float kd[8];
    {
        const float* kp = &kdig[(bhT + k0 + l) * KD];
        *(float4*)&kd[0] = *(const float4*)kp;
        *(float4*)&kd[4] = *(const float4*)(kp + 4);
    }
    __syncthreads();

    const bool diag = (kt == c);
    for (int qi = 0; qi < 16; ++qi) {
        const int qrow = w * 16 + qi;
        float qd[8];
        *(float4*)&qd[0] = *(const float4*)&qds[qrow * 8];
        *(float4*)&qd[4] = *(const float4*)&qds[qrow * 8 + 4];
        float cum = 1.f, lcp = 0.f;
        #pragma unroll
        for (int jj = 0; jj < 8; ++jj) {
            float d = qd[jj] - kd[jj];
            cum *= exp2f(-BETA_LOG2E * d * d);
            lcp += cum;
        }
        float wgt = exp2f(lcp);
        if (diag && l > qrow) wgt = 0.f;
        Ps[qrow * 64 + (((l >> 3) ^ (qi & 7)) << 3) + (l & 7)] = f2bf(wgt);
    }
    __syncthreads();

    const int wr = (w >> 1) * 32, wc = (w & 1) * 32;
    f32x4 acc[2][2], accd[2];
    #pragma unroll
    for (int i = 0; i < 2; ++i) {
        accd[i] = (f32x4){0.f, 0.f, 0.f, 0.f};
        #pragma unroll
        for (int j = 0; j < 2; ++j) acc[i][j] = (f32x4){0.f, 0.f, 0.f, 0.f};
    }
    bf16x8 ones;
    #pragma unroll
    for (int i = 0; i < 8; ++i) ones[i] = (short)0x3F80;

    #pragma unroll
    for (int kh = 0; kh < 2; ++kh) {
        bf16x8 af[2], bfr[2];
        #pragma unroll
        for (int i = 0; i < 2; ++i) {
            const int ra = wr + i * 16 + (l & 15);
            const int sa = (kh * 4 + (l >> 4)) ^ (ra & 7);
            af[i] = *(const bf16x8*)&Ps[ra * 64 + sa * 8];
            const int rb = wc + i * 16 + (l & 15);
            const int sb = (kh * 4 + (l >> 4)) ^ (rb & 7);
            bfr[i] = *(const bf16x8*)&Vs[rb * 64 + sb * 8];
        }
        #pragma unroll
        for (int i = 0; i < 2; ++i) {
            accd[i] = __builtin_amdgcn_mfma_f32_16x16x32_bf16(af[i], ones, accd[i], 0, 0, 0);
            #pragma unroll
            for (int j = 0; j < 2; ++j)
                acc[i][j] = __builtin_amdgcn_mfma_f32_16x16x32_bf16(
                    af[i], bfr[j], acc[i][j], 0, 0, 0);
        }
    }

    const int task = bh * 36 + blockIdx.x;
    u16* pa = pacc + (size_t)task * 4096;
    #pragma unroll
    for (int i = 0; i < 2; ++i) {
        const int row = wr + i * 16 + (l >> 4) * 4;
        #pragma unroll
        for (int j = 0; j < 2; ++j) {
            const int col = wc + j * 16 + (l & 15);
            #pragma unroll
            for (int r = 0; r < 4; ++r)
                pa[(size_t)(row + r) * 64 + col] = f2bf(acc[i][j][r]);
        }
        if ((l & 15) == 0) {
            #pragma unroll
            for (int r = 0; r < 4; ++r)
                pdeng[(size_t)task * 64 + row + r] = accd[i][r];
        }
    }
}

// ---------------------------------------------------------------------------
// Combine partials over kt, normalize, write y as bf16 (B,T,C).
// ---------------------------------------------------------------------------
__global__ __launch_bounds__(256)
void attn_combine(const u16* __restrict__ pacc, const float* __restrict__ pdeng,
                  u16* __restrict__ y)
{
    const int c = blockIdx.x, h = blockIdx.y, b = blockIdx.z;
    const int tid = threadIdx.x;
    const int r = tid >> 2, dg = (tid & 3) * 16;
    const int base = (b * NH + h) * 36 + c * (c + 1) / 2;

    float acc[16] = {};
    float den = 0.f;
    for (int kt = 0; kt <= c; ++kt) {
        const u16* pa = pacc + (size_t)(base + kt) * 4096 + r * 64 + dg;
        ushort4 v0 = *(const ushort4*)(pa + 0);
        ushort4 v1 = *(const ushort4*)(pa + 4);
        ushort4 v2 = *(const ushort4*)(pa + 8);
        ushort4 v3 = *(const ushort4*)(pa + 12);
        acc[0]  += bf2f(v0.x); acc[1]  += bf2f(v0.y);
        acc[2]  += bf2f(v0.z); acc[3]  += bf2f(v0.w);
        acc[4]  += bf2f(v1.x); acc[5]  += bf2f(v1.y);
        acc[6]  += bf2f(v1.z); acc[7]  += bf2f(v1.w);
        acc[8]  += bf2f(v2.x); acc[9]  += bf2f(v2.y);
        acc[10] += bf2f(v2.z); acc[11] += bf2f(v2.w);
        acc[12] += bf2f(v3.x); acc[13] += bf2f(v3.y);
        acc[14] += bf2f(v3.z); acc[15] += bf2f(v3.w);
        den += pdeng[(size_t)(base + kt) * 64 + r];
    }
    float inv = 1.f / fmaxf(den, 1e-9f);

    u16* yr = y + ((size_t)(b * T_SEQ + c * 64 + r)) * CDIM + h * DH + dg;
    uint4 p0, p1;
    p0.x = f2bf(acc[0] * inv)  | ((unsigned)f2bf(acc[1] * inv)  << 16);
    p0.y = f2bf(acc[2] * inv)  | ((unsigned)f2bf(acc[3] * inv)  << 16);
    p0.z = f2bf(acc[4] * inv)  | ((unsigned)f2bf(acc[5] * inv)  << 16);
    p0.w = f2bf(acc[6] * inv)  | ((unsigned)f2bf(acc[7] * inv)  << 16);
    p1.x = f2bf(acc[8] * inv)  | ((unsigned)f2bf(acc[9] * inv)  << 16);
    p1.y = f2bf(acc[10] * inv) | ((unsigned)f2bf(acc[11] * inv) << 16);
    p1.z = f2bf(acc[12] * inv) | ((unsigned)f2bf(acc[13] * inv) << 16);
    p1.w = f2bf(acc[14] * inv) | ((unsigned)f2bf(acc[15] * inv) << 16);
    *(uint4*)(yr + 0) = p0;
    *(uint4*)(yr + 8) = p1;
}

// ---------------------------------------------------------------------------
// Output projection GEMM, 32x64 tiles (grid 16 x 32 = 512 blocks, 2/CU).
// Wave w: output rows (w&1)*16..+16, cols (w>>1)*32..+32.
// ---------------------------------------------------------------------------
__global__ __launch_bounds__(256)
void gemm_proj(const u16* __restrict__ A, const u16* __restrict__ Bt,
               float* __restrict__ C)
{
    __shared__ u16 As[32 * 64];   // 4KB
    __shared__ u16 Bs[64 * 64];   // 8KB

    const int tid = threadIdx.x;
    const int l = tid & 63, w = tid >> 6;
    const int m0 = blockIdx.y * 32, n0 = blockIdx.x * 64;
    const int wr = (w & 1) * 16, wc = (w >> 1) * 32;
    const int srow = l >> 3;
    const int sslot = (l & 7) ^ srow;

    f32x4 acc[2];
    acc[0] = (f32x4){0.f, 0.f, 0.f, 0.f};
    acc[1] = (f32x4){0.f, 0.f, 0.f, 0.f};

    for (int k0 = 0; k0 < CDIM; k0 += 64) {
        __syncthreads();
        {
            const int rowa = w * 8 + srow;
            gload_lds16(A + (size_t)(m0 + rowa) * CDIM + k0 + sslot * 8,
                        &As[(w * 8) * 64]);
        }
        #pragma unroll
        for (int q = 0; q < 2; ++q) {
            const int row = w * 16 + q * 8 + srow;
            gload_lds16(Bt + (size_t)(n0 + row) * CDIM + k0 + sslot * 8,
                        &Bs[(w * 16 + q * 8) * 64]);
        }
        __syncthreads();

        bf16x8 af[2], bfr[2][2];
        #pragma unroll
        for (int kh = 0; kh < 2; ++kh) {
            const int ra = wr + (l & 15);
            const int sa = (kh * 4 + (l >> 4)) ^ (ra & 7);
            af[kh] = *(const bf16x8*)&As[ra * 64 + sa * 8];
            #pragma unroll
            for (int j = 0; j < 2; ++j) {
                const int rb = wc + j * 16 + (l & 15);
                const int sb = (kh * 4 + (l >> 4)) ^ (rb & 7);
                bfr[j][kh] = *(const bf16x8*)&Bs[rb * 64 + sb * 8];
            }
        }
        #pragma unroll
        for (int kh = 0; kh < 2; ++kh)
            #pragma unroll
            for (int j = 0; j < 2; ++j)
                acc[j] = __builtin_amdgcn_mfma_f32_16x16x32_bf16(
                    af[kh], bfr[j][kh], acc[j], 0, 0, 0);
    }

    #pragma unroll
    for (int j = 0; j < 2; ++j) {
        const int row = m0 + wr + (l >> 4) * 4;
        const int col = n0 + wc + j * 16 + (l & 15);
        #pragma unroll
        for (int r = 0; r < 4; ++r)
            C[(size_t)(row + r) * CDIM + col] = acc[j][r];
    }
}

// ---------------------------------------------------------------------------
extern "C" void kernel_launch(void* const* d_in, const int* in_sizes, int n_in,
                              void* d_out, int out_size, void* d_ws, size_t ws_size,
                              hipStream_t stream)
{
    (void)in_sizes; (void)n_in; (void)out_size; (void)ws_size;
    const float* x    = (const float*)d_in[0];
    const float* cosp = (const float*)d_in[1];
    const float* sinp = (const float*)d_in[2];
    const float* Wq   = (const float*)d_in[3];
    const float* Wk   = (const float*)d_in[4];
    const float* Wv   = (const float*)d_in[5];
    const float* Wo   = (const float*)d_in[6];
    const float* Wdq  = (const float*)d_in[7];
    const float* Wdk  = (const float*)d_in[8];
    float* out = (float*)d_out;

    const int M = BB * T_SEQ;                 // 1024
    const size_t MC = (size_t)M * CDIM;       // 1M elems
    char* p = (char*)d_ws;
    float* qdig = (float*)p; p += (size_t)M * NH * KD * 4;   // 512KB
    float* kdig = (float*)p; p += (size_t)M * NH * KD * 4;   // 512KB
    u16* xb   = (u16*)p; p += MC * 2;
    u16* wqt  = (u16*)p; p += MC * 2;
    u16* wkt  = (u16*)p; p += MC * 2;
    u16* wvt  = (u16*)p; p += MC * 2;
    u16* wot  = (u16*)p; p += MC * 2;
    u16* Vt   = (u16*)p; p += MC * 2;         // [b][h][d][t] bf16, 2MB
    u16* ybuf = (u16*)p; p += MC * 2;
    u16* pacc = (u16*)p; p += (size_t)1152 * 4096 * 2;       // 9.4MB bf16
    float* pdeng = (float*)p; p += (size_t)1152 * 64 * 4;

    dim3 blk(256);
    prep_kernel<<<dim3(32, 32, 5), blk, 0, stream>>>(
        x, Wq, Wk, Wv, Wo, xb, wqt, wkt, wvt, wot);
    gemm_qkv_fused<<<dim3(16, 16, 3), blk, 0, stream>>>(
        xb, wqt, wkt, wvt, cosp, sinp, Wdq, Wdk, qdig, kdig, Vt);
    attn_partial<<<dim3(36, NH, BB), blk, 0, stream>>>(
        qdig, kdig, Vt, pacc, pdeng);
    attn_combine<<<dim3(8, NH, BB), blk, 0, stream>>>(pacc, pdeng, ybuf);
    gemm_proj<<<dim3(16, 32), blk, 0, stream>>>(ybuf, wot, out);
}

// Round 6
// 58.725 us; speedup vs baseline: 4.3044x; 1.0116x over previous
//
#include <hip/hip_runtime.h>

#define T_SEQ 512
#define CDIM  1024
#define NH    16
#define DH    64
#define BB    2
#define KD    8

#define BETA_LOG2E 46.16624131f   // 32*log2(e)
#define LOG2E      1.4426950408889634f

typedef unsigned short u16;
typedef __attribute__((ext_vector_type(8))) short bf16x8;
typedef __attribute__((ext_vector_type(4))) float f32x4;

__device__ inline u16 f2bf(float f) {
    unsigned int u = __builtin_bit_cast(unsigned int, f);
    unsigned int r = (u + 0x7fffu + ((u >> 16) & 1u)) >> 16;
    return (u16)r;
}
__device__ inline float bf2f(u16 v) {
    unsigned int u = ((unsigned int)v) << 16;
    return __builtin_bit_cast(float, u);
}

__device__ inline void gload_lds16(const void* g, void* l) {
    __builtin_amdgcn_global_load_lds(
        (const __attribute__((address_space(1))) void*)g,
        (__attribute__((address_space(3))) void*)l, 16, 0, 0);
}

// ---------------------------------------------------------------------------
// Prep: z=0..3 -> transpose W to bf16 [N][K]; z=4 -> convert x to bf16.
// ---------------------------------------------------------------------------
__global__ __launch_bounds__(256)
void prep_kernel(const float* __restrict__ x,
                 const float* __restrict__ W0, const float* __restrict__ W1,
                 const float* __restrict__ W2, const float* __restrict__ W3,
                 u16* __restrict__ xb,
                 u16* __restrict__ T0, u16* __restrict__ T1,
                 u16* __restrict__ T2, u16* __restrict__ T3)
{
    const int tid = threadIdx.x;
    if (blockIdx.z == 4) {
        const int row = blockIdx.y * 32 + (tid >> 3);
        const int col = blockIdx.x * 32 + (tid & 7) * 4;
        float4 v = *(const float4*)&x[(size_t)row * CDIM + col];
        ushort4 o = { f2bf(v.x), f2bf(v.y), f2bf(v.z), f2bf(v.w) };
        *(ushort4*)&xb[(size_t)row * CDIM + col] = o;
        return;
    }
    __shared__ u16 tile[32][33];
    const float* W = (blockIdx.z == 0) ? W0 : (blockIdx.z == 1) ? W1
                   : (blockIdx.z == 2) ? W2 : W3;
    u16* Tt        = (blockIdx.z == 0) ? T0 : (blockIdx.z == 1) ? T1
                   : (blockIdx.z == 2) ? T2 : T3;
    const int k0 = blockIdx.y * 32, n0 = blockIdx.x * 32;
    const int r = tid >> 3, c4 = (tid & 7) * 4;

    float4 v = *(const float4*)&W[(size_t)(k0 + r) * CDIM + n0 + c4];
    tile[r][c4 + 0] = f2bf(v.x);
    tile[r][c4 + 1] = f2bf(v.y);
    tile[r][c4 + 2] = f2bf(v.z);
    tile[r][c4 + 3] = f2bf(v.w);
    __syncthreads();
    ushort4 o;
    o.x = tile[c4 + 0][r];
    o.y = tile[c4 + 1][r];
    o.z = tile[c4 + 2][r];
    o.w = tile[c4 + 3][r];
    *(ushort4*)&Tt[(size_t)(n0 + r) * CDIM + k0 + c4] = o;
}

// ---------------------------------------------------------------------------
// Fused QKV GEMM. 64x64 tile, BK=128, 4 waves of 32x32, XCD-swizzled grid.
// z=0 (Q) / z=1 (K): epilogue RoPE + RMS-norm + digit projection.
// z=2 (V): epilogue writes V^T bf16, layout [b][h][d][t].
// ---------------------------------------------------------------------------
__global__ __launch_bounds__(256)
void gemm_qkv_fused(const u16* __restrict__ A,
                    const u16* __restrict__ Bq, const u16* __restrict__ Bk,
                    const u16* __restrict__ Bv,
                    const float* __restrict__ cosp, const float* __restrict__ sinp,
                    const float* __restrict__ Wdq, const float* __restrict__ Wdk,
                    float* __restrict__ qdig, float* __restrict__ kdig,
                    u16* __restrict__ Vt)
{
    __shared__ __align__(16) char smem[32768];  // 2x 64x128 bf16 tiles / Cf f32
    u16* As = (u16*)smem;
    u16* Bs = As + 8192;
    float* Cf = (float*)smem;    // [64][65] after MFMA phase

    // XCD swizzle: 768 blocks -> 96 consecutive per XCD
    const int wg = (blockIdx.x & 7) * 96 + (blockIdx.x >> 3);
    const int z = wg >> 8;
    const int rem = wg & 255;
    const int h = rem & 15;                 // n-tile == head
    const int m0 = (rem >> 4) * 64;
    const int n0 = h * 64;

    const u16* Bt = (z == 0) ? Bq : (z == 1) ? Bk : Bv;

    const int tid = threadIdx.x;
    const int l = tid & 63, w = tid >> 6;
    const int wr = (w >> 1) * 32, wc = (w & 1) * 32;

    f32x4 acc[2][2];
    #pragma unroll
    for (int i = 0; i < 2; ++i)
        #pragma unroll
        for (int j = 0; j < 2; ++j)
            acc[i][j] = (f32x4){0.f, 0.f, 0.f, 0.f};

    for (int k0 = 0; k0 < CDIM; k0 += 128) {
        __syncthreads();
        #pragma unroll
        for (int q = 0; q < 4; ++q) {
            const int row = w * 16 + q * 4 + (l >> 4);
            const int slot = (l & 15) ^ (row & 15);
            gload_lds16(A  + (size_t)(m0 + row) * CDIM + k0 + slot * 8,
                        &As[(w * 16 + q * 4) * 128]);
            gload_lds16(Bt + (size_t)(n0 + row) * CDIM + k0 + slot * 8,
                        &Bs[(w * 16 + q * 4) * 128]);
        }
        __syncthreads();

        #pragma unroll
        for (int kh = 0; kh < 4; ++kh) {
            bf16x8 af[2], bfr[2];
            #pragma unroll
            for (int i = 0; i < 2; ++i) {
                const int ra = wr + i * 16 + (l & 15);
                const int sa = (kh * 4 + (l >> 4)) ^ (ra & 15);
                af[i] = *(const bf16x8*)&As[ra * 128 + sa * 8];
                const int rb = wc + i * 16 + (l & 15);
                const int sb = (kh * 4 + (l >> 4)) ^ (rb & 15);
                bfr[i] = *(const bf16x8*)&Bs[rb * 128 + sb * 8];
            }
            #pragma unroll
            for (int i = 0; i < 2; ++i)
                #pragma unroll
                for (int j = 0; j < 2; ++j)
                    acc[i][j] = __builtin_amdgcn_mfma_f32_16x16x32_bf16(
                        af[i], bfr[j], acc[i][j], 0, 0, 0);
        }
    }

    __syncthreads();   // staging reads done; smem becomes Cf

    if (z == 2) {
        #pragma unroll
        for (int i = 0; i < 2; ++i)
            #pragma unroll
            for (int j = 0; j < 2; ++j) {
                const int mm = wr + i * 16 + (l >> 4) * 4;
                const int dd = wc + j * 16 + (l & 15);
                #pragma unroll
                for (int r = 0; r < 4; ++r)
                    Cf[dd * 65 + mm + r] = acc[i][j][r];
            }
        __syncthreads();
        const int b = m0 >> 9, t0 = m0 & (T_SEQ - 1);
        u16* vbase = Vt + ((size_t)(b * NH + h) * 64) * T_SEQ;
        #pragma unroll
        for (int it = 0; it < 16; ++it) {
            const int d = it * 4 + w;
            vbase[(size_t)d * T_SEQ + t0 + l] = f2bf(Cf[d * 65 + l]);
        }
        return;
    }

    // Q/K path: Cf[m][d], stride 65
    #pragma unroll
    for (int i = 0; i < 2; ++i)
        #pragma unroll
        for (int j = 0; j < 2; ++j) {
            const int mm = wr + i * 16 + (l >> 4) * 4;
            const int dd = wc + j * 16 + (l & 15);
            #pragma unroll
            for (int r = 0; r < 4; ++r)
                Cf[(mm + r) * 65 + dd] = acc[i][j][r];
        }

    const float* Wd = z ? Wdk : Wdq;
    float* dig = z ? kdig : qdig;

    const int dl = l & 15, rq = l >> 4;
    float wreg[4][8];   // Wd rows dl, dl+16, dl+32, dl+48
    #pragma unroll
    for (int d4 = 0; d4 < 4; ++d4) {
        *(float4*)&wreg[d4][0] = *(const float4*)&Wd[(dl + d4 * 16) * 8];
        *(float4*)&wreg[d4][4] = *(const float4*)&Wd[(dl + d4 * 16) * 8 + 4];
    }
    __syncthreads();

    for (int g = 0; g < 4; ++g) {
        const int m = w * 16 + g * 4 + rq;
        const int mg = m0 + m;
        const int b = mg >> 9, t = mg & (T_SEQ - 1);

        const float* cr = &Cf[m * 65];
        float r0 = cr[dl], r1 = cr[dl + 16], r2 = cr[dl + 32], r3 = cr[dl + 48];
        float c0 = cosp[t * 32 + dl], c1 = cosp[t * 32 + dl + 16];
        float s0 = sinp[t * 32 + dl], s1 = sinp[t * 32 + dl + 16];
        float v0 = r0 * c0 - r2 * s0;
        float v1 = r1 * c1 - r3 * s1;
        float v2 = r0 * s0 + r2 * c0;
        float v3 = r1 * s1 + r3 * c1;

        float ss = v0 * v0 + v1 * v1 + v2 * v2 + v3 * v3;
        #pragma unroll
        for (int off = 1; off < 16; off <<= 1) ss += __shfl_xor(ss, off);
        float sc = rsqrtf(ss * (1.0f / 64.0f) + 1e-6f);
        v0 *= sc; v1 *= sc; v2 *= sc; v3 *= sc;

        float zz[8];
        #pragma unroll
        for (int j = 0; j < 8; ++j)
            zz[j] = v0 * wreg[0][j] + v1 * wreg[1][j] + v2 * wreg[2][j] + v3 * wreg[3][j];
        #pragma unroll
        for (int j = 0; j < 8; ++j) {
            #pragma unroll
            for (int off = 1; off < 16; off <<= 1) zz[j] += __shfl_xor(zz[j], off);
        }
        float zsel = zz[0];
        #pragma unroll
        for (int j = 1; j < 8; ++j) zsel = (dl == j) ? zz[j] : zsel;
        if (dl < 8)
            dig[((size_t)(b * NH + h) * T_SEQ + t) * KD + dl] =
                1.0f / (1.0f + exp2f(-LOG2E * zsel));
    }
}

// ---------------------------------------------------------------------------
// Ultrametric attention partial (MFMA). One 64q x 64k tile per block.
// Flat 1152-block grid with XCD swizzle. Partial PV bf16; denom fp32.
// ---------------------------------------------------------------------------
__global__ __launch_bounds__(256)
void attn_partial(const float* __restrict__ qdig, const float* __restrict__ kdig,
                  const u16* __restrict__ Vt,
                  u16* __restrict__ pacc, float* __restrict__ pdeng)
{
    __shared__ u16 Vs[4096];    // [d][k] swizzled, 8KB
    __shared__ u16 Ps[4096];    // [q][k] swizzled, 8KB
    __shared__ float qds[512];  // [q][8]

    const int tid = threadIdx.x;
    const int w = tid >> 6, l = tid & 63;

    // XCD swizzle: 1152 blocks -> 144 consecutive per XCD
    const int wg = (blockIdx.x & 7) * 144 + (blockIdx.x >> 3);
    const int tile = wg % 36;
    const int bh = wg / 36;
    const size_t bhT = (size_t)bh * T_SEQ;

    int id = tile, c = 0;
    while (id >= c + 1) { id -= (c + 1); ++c; }
    const int kt = id;
    const int k0 = kt * 64;

    const int srow = l >> 3, sslot = (l & 7) ^ srow;
    #pragma unroll
    for (int q2 = 0; q2 < 2; ++q2) {
        const int R0 = w * 16 + q2 * 8;
        gload_lds16(Vt + ((size_t)bh * 64 + R0 + srow) * T_SEQ + k0 + sslot * 8,
                    &Vs[R0 * 64]);
    }
    *(float2*)&qds[tid * 2] = *(const float2*)&qdig[(bhT + c * 64) * KD + tid * 2];

    float kd[8];
    {
        const float* kp = &kdig[(bhT + k0 + l) * KD];
        *(float4*)&kd[0] = *(const float4*)kp;
        *(float4*)&kd[4] = *(const float4*)(kp + 4);
    }
    __syncthreads();

    const bool diag = (kt == c);
    for (int qi = 0; qi < 16; ++qi) {
        const int qrow = w * 16 + qi;
        float qd[8];
        *(float4*)&qd[0] = *(const float4*)&qds[qrow * 8];
        *(float4*)&qd[4] = *(const float4*)&qds[qrow * 8 + 4];
        float S = 0.f, lcp = 0.f;
        #pragma unroll
        for (int jj = 0; jj < 8; ++jj) {
            float d = qd[jj] - kd[jj];
            S += d * d;
            lcp += exp2f(-BETA_LOG2E * S);
        }
        float wgt = exp2f(lcp);
        if (diag && l > qrow) wgt = 0.f;
        Ps[qrow * 64 + (((l >> 3) ^ (qi & 7)) << 3) + (l & 7)] = f2bf(wgt);
    }
    __syncthreads();

    const int wr = (w >> 1) * 32, wc = (w & 1) * 32;
    f32x4 acc[2][2], accd[2];
    #pragma unroll
    for (int i = 0; i < 2; ++i) {
        accd[i] = (f32x4){0.f, 0.f, 0.f, 0.f};
        #pragma unroll
        for (int j = 0; j < 2; ++j) acc[i][j] = (f32x4){0.f, 0.f, 0.f, 0.f};
    }
    bf16x8 ones;
    #pragma unroll
    for (int i = 0; i < 8; ++i) ones[i] = (short)0x3F80;

    #pragma unroll
    for (int kh = 0; kh < 2; ++kh) {
        bf16x8 af[2], bfr[2];
        #pragma unroll
        for (int i = 0; i < 2; ++i) {
            const int ra = wr + i * 16 + (l & 15);
            const int sa = (kh * 4 + (l >> 4)) ^ (ra & 7);
            af[i] = *(const bf16x8*)&Ps[ra * 64 + sa * 8];
            const int rb = wc + i * 16 + (l & 15);
            const int sb = (kh * 4 + (l >> 4)) ^ (rb & 7);
            bfr[i] = *(const bf16x8*)&Vs[rb * 64 + sb * 8];
        }
        #pragma unroll
        for (int i = 0; i < 2; ++i) {
            accd[i] = __builtin_amdgcn_mfma_f32_16x16x32_bf16(af[i], ones, accd[i], 0, 0, 0);
            #pragma unroll
            for (int j = 0; j < 2; ++j)
                acc[i][j] = __builtin_amdgcn_mfma_f32_16x16x32_bf16(
                    af[i], bfr[j], acc[i][j], 0, 0, 0);
        }
    }

    const int task = bh * 36 + tile;
    u16* pa = pacc + (size_t)task * 4096;
    #pragma unroll
    for (int i = 0; i < 2; ++i) {
        const int row = wr + i * 16 + (l >> 4) * 4;
        #pragma unroll
        for (int j = 0; j < 2; ++j) {
            const int col = wc + j * 16 + (l & 15);
            #pragma unroll
            for (int r = 0; r < 4; ++r)
                pa[(size_t)(row + r) * 64 + col] = f2bf(acc[i][j][r]);
        }
        if ((l & 15) == 0) {
            #pragma unroll
            for (int r = 0; r < 4; ++r)
                pdeng[(size_t)task * 64 + row + r] = accd[i][r];
        }
    }
}

// ---------------------------------------------------------------------------
// Combine partials over kt, normalize, write y bf16 (B,T,C).
// Grid (16, NH, BB): x = c*2 + column-half (2 blocks/CU).
// ---------------------------------------------------------------------------
__global__ __launch_bounds__(256)
void attn_combine(const u16* __restrict__ pacc, const float* __restrict__ pdeng,
                  u16* __restrict__ y)
{
    const int c = blockIdx.x >> 1, half = blockIdx.x & 1;
    const int h = blockIdx.y, b = blockIdx.z;
    const int tid = threadIdx.x;
    const int r = tid >> 2, cg = (tid & 3) * 8 + half * 32;
    const int base = (b * NH + h) * 36 + c * (c + 1) / 2;

    float acc[8] = {};
    float den = 0.f;
    for (int kt = 0; kt <= c; ++kt) {
        const u16* pa = pacc + (size_t)(base + kt) * 4096 + r * 64 + cg;
        ushort4 v0 = *(const ushort4*)(pa + 0);
        ushort4 v1 = *(const ushort4*)(pa + 4);
        acc[0] += bf2f(v0.x); acc[1] += bf2f(v0.y);
        acc[2] += bf2f(v0.z); acc[3] += bf2f(v0.w);
        acc[4] += bf2f(v1.x); acc[5] += bf2f(v1.y);
        acc[6] += bf2f(v1.z); acc[7] += bf2f(v1.w);
        den += pdeng[(size_t)(base + kt) * 64 + r];
    }
    float inv = 1.f / fmaxf(den, 1e-9f);

    u16* yr = y + ((size_t)(b * T_SEQ + c * 64 + r)) * CDIM + h * DH + cg;
    uint4 p;
    p.x = f2bf(acc[0] * inv) | ((unsigned)f2bf(acc[1] * inv) << 16);
    p.y = f2bf(acc[2] * inv) | ((unsigned)f2bf(acc[3] * inv) << 16);
    p.z = f2bf(acc[4] * inv) | ((unsigned)f2bf(acc[5] * inv) << 16);
    p.w = f2bf(acc[6] * inv) | ((unsigned)f2bf(acc[7] * inv) << 16);
    *(uint4*)yr = p;
}

// ---------------------------------------------------------------------------
// Output projection GEMM, 32x64 tiles, BK=128, XCD-swizzled 512-block grid.
// ---------------------------------------------------------------------------
__global__ __launch_bounds__(256)
void gemm_proj(const u16* __restrict__ A, const u16* __restrict__ Bt,
               float* __restrict__ C)
{
    __shared__ u16 As[32 * 128];   // 8KB
    __shared__ u16 Bs[64 * 128];   // 16KB

    // XCD swizzle: 512 blocks -> 64 consecutive per XCD
    const int wg = (blockIdx.x & 7) * 64 + (blockIdx.x >> 3);
    const int n0 = (wg & 15) * 64;
    const int m0 = (wg >> 4) * 32;

    const int tid = threadIdx.x;
    const int l = tid & 63, w = tid >> 6;
    const int wr = (w & 1) * 16, wc = (w >> 1) * 32;

    f32x4 acc[2];
    acc[0] = (f32x4){0.f, 0.f, 0.f, 0.f};
    acc[1] = (f32x4){0.f, 0.f, 0.f, 0.f};

    for (int k0 = 0; k0 < CDIM; k0 += 128) {
        __syncthreads();
        #pragma unroll
        for (int q = 0; q < 2; ++q) {
            const int rowa = w * 8 + q * 4 + (l >> 4);
            const int slota = (l & 15) ^ (rowa & 15);
            gload_lds16(A + (size_t)(m0 + rowa) * CDIM + k0 + slota * 8,
                        &As[(w * 8 + q * 4) * 128]);
        }
        #pragma unroll
        for (int q = 0; q < 4; ++q) {
            const int row = w * 16 + q * 4 + (l >> 4);
            const int slot = (l & 15) ^ (row & 15);
            gload_lds16(Bt + (size_t)(n0 + row) * CDIM + k0 + slot * 8,
                        &Bs[(w * 16 + q * 4) * 128]);
        }
        __syncthreads();

        #pragma unroll
        for (int kh = 0; kh < 4; ++kh) {
            const int ra = wr + (l & 15);
            const int sa = (kh * 4 + (l >> 4)) ^ (ra & 15);
            bf16x8 af = *(const bf16x8*)&As[ra * 128 + sa * 8];
            #pragma unroll
            for (int j = 0; j < 2; ++j) {
                const int rb = wc + j * 16 + (l & 15);
                const int sb = (kh * 4 + (l >> 4)) ^ (rb & 15);
                bf16x8 bfr = *(const bf16x8*)&Bs[rb * 128 + sb * 8];
                acc[j] = __builtin_amdgcn_mfma_f32_16x16x32_bf16(
                    af, bfr, acc[j], 0, 0, 0);
            }
        }
    }

    #pragma unroll
    for (int j = 0; j < 2; ++j) {
        const int row = m0 + wr + (l >> 4) * 4;
        const int col = n0 + wc + j * 16 + (l & 15);
        #pragma unroll
        for (int r = 0; r < 4; ++r)
            C[(size_t)(row + r) * CDIM + col] = acc[j][r];
    }
}

// ---------------------------------------------------------------------------
extern "C" void kernel_launch(void* const* d_in, const int* in_sizes, int n_in,
                              void* d_out, int out_size, void* d_ws, size_t ws_size,
                              hipStream_t stream)
{
    (void)in_sizes; (void)n_in; (void)out_size; (void)ws_size;
    const float* x    = (const float*)d_in[0];
    const float* cosp = (const float*)d_in[1];
    const float* sinp = (const float*)d_in[2];
    const float* Wq   = (const float*)d_in[3];
    const float* Wk   = (const float*)d_in[4];
    const float* Wv   = (const float*)d_in[5];
    const float* Wo   = (const float*)d_in[6];
    const float* Wdq  = (const float*)d_in[7];
    const float* Wdk  = (const float*)d_in[8];
    float* out = (float*)d_out;

    const int M = BB * T_SEQ;                 // 1024
    const size_t MC = (size_t)M * CDIM;       // 1M elems
    char* p = (char*)d_ws;
    float* qdig = (float*)p; p += (size_t)M * NH * KD * 4;   // 512KB
    float* kdig = (float*)p; p += (size_t)M * NH * KD * 4;   // 512KB
    u16* xb   = (u16*)p; p += MC * 2;
    u16* wqt  = (u16*)p; p += MC * 2;
    u16* wkt  = (u16*)p; p += MC * 2;
    u16* wvt  = (u16*)p; p += MC * 2;
    u16* wot  = (u16*)p; p += MC * 2;
    u16* Vt   = (u16*)p; p += MC * 2;         // [b][h][d][t] bf16, 2MB
    u16* ybuf = (u16*)p; p += MC * 2;
    u16* pacc = (u16*)p; p += (size_t)1152 * 4096 * 2;       // 9.4MB bf16
    float* pdeng = (float*)p; p += (size_t)1152 * 64 * 4;

    dim3 blk(256);
    prep_kernel<<<dim3(32, 32, 5), blk, 0, stream>>>(
        x, Wq, Wk, Wv, Wo, xb, wqt, wkt, wvt, wot);
    gemm_qkv_fused<<<dim3(768), blk, 0, stream>>>(
        xb, wqt, wkt, wvt, cosp, sinp, Wdq, Wdk, qdig, kdig, Vt);
    attn_partial<<<dim3(1152), blk, 0, stream>>>(
        qdig, kdig, Vt, pacc, pdeng);
    attn_combine<<<dim3(16, NH, BB), blk, 0, stream>>>(pacc, pdeng, ybuf);
    gemm_proj<<<dim3(512), blk, 0, stream>>>(ybuf, wot, out);
}